// Round 2
// baseline (3856.308 us; speedup 1.0000x reference)
//
#include <hip/hip_runtime.h>

#define H 256
#define NB 6
#define IN_DIM 128
#define BM 128
#define BN 64
#define BK 16

__device__ __forceinline__ float fsigmoid(float x) {
    return 1.0f / (1.0f + __expf(-x));
}
__device__ __forceinline__ float ftanh(float x) {
    x = fminf(15.0f, fmaxf(-15.0f, x));
    float e = __expf(2.0f * x);
    return (e - 1.0f) / (e + 1.0f);
}

// ---------------------------------------------------------------------------
// Generic fp32 tiled GEMM: C[M,256] = A[M,K] @ B[K,256] (+ bias)
// A contiguous [M,K] (lda=K); B row stride = H. 128x64 tile, 256 threads.
// ---------------------------------------------------------------------------
template<bool HAS_BIAS>
__global__ __launch_bounds__(256) void gemm_kernel(
    const float* __restrict__ A, const float* __restrict__ B,
    const float* __restrict__ bias, float* __restrict__ C,
    int M, int K)
{
    __shared__ float As[BK][BM + 4];
    __shared__ float Bs[BK][BN];

    const int tid = threadIdx.x;
    const int m0 = blockIdx.x * BM;
    const int n0 = blockIdx.y * BN;
    const int ty = tid >> 4;
    const int tx = tid & 15;
    const int lar = tid >> 2;
    const int lac = (tid & 3) << 2;
    const int lbr = tid >> 4;
    const int lbc = (tid & 15) << 2;

    float4 acc[8];
#pragma unroll
    for (int i = 0; i < 8; i++) acc[i] = make_float4(0.f, 0.f, 0.f, 0.f);

    for (int k0 = 0; k0 < K; k0 += BK) {
        const int r0 = m0 + lar, r1 = r0 + 64;
        float4 a0 = make_float4(0.f,0.f,0.f,0.f), a1 = a0;
        if (r0 < M) a0 = *(const float4*)(A + (size_t)r0 * K + k0 + lac);
        if (r1 < M) a1 = *(const float4*)(A + (size_t)r1 * K + k0 + lac);
        const float4 b = *(const float4*)(B + (size_t)(k0 + lbr) * H + n0 + lbc);

        As[lac + 0][lar] = a0.x; As[lac + 1][lar] = a0.y;
        As[lac + 2][lar] = a0.z; As[lac + 3][lar] = a0.w;
        As[lac + 0][lar + 64] = a1.x; As[lac + 1][lar + 64] = a1.y;
        As[lac + 2][lar + 64] = a1.z; As[lac + 3][lar + 64] = a1.w;
        *(float4*)&Bs[lbr][lbc] = b;
        __syncthreads();

#pragma unroll
        for (int k = 0; k < BK; k++) {
            const float4 bv = *(const float4*)&Bs[k][tx << 2];
            const float4 alo = *(const float4*)&As[k][ty << 3];
            const float4 ahi = *(const float4*)&As[k][(ty << 3) + 4];
            const float av[8] = {alo.x, alo.y, alo.z, alo.w, ahi.x, ahi.y, ahi.z, ahi.w};
#pragma unroll
            for (int i = 0; i < 8; i++) {
                acc[i].x = fmaf(av[i], bv.x, acc[i].x);
                acc[i].y = fmaf(av[i], bv.y, acc[i].y);
                acc[i].z = fmaf(av[i], bv.z, acc[i].z);
                acc[i].w = fmaf(av[i], bv.w, acc[i].w);
            }
        }
        __syncthreads();
    }

    float4 bv = make_float4(0.f, 0.f, 0.f, 0.f);
    if (HAS_BIAS) bv = *(const float4*)(bias + n0 + (tx << 2));
#pragma unroll
    for (int i = 0; i < 8; i++) {
        const int row = m0 + (ty << 3) + i;
        if (row < M) {
            float4 o = acc[i];
            o.x += bv.x; o.y += bv.y; o.z += bv.z; o.w += bv.w;
            *(float4*)(C + (size_t)row * H + n0 + (tx << 2)) = o;
        }
    }
}

// ---------------------------------------------------------------------------
// Step 0 elementwise: h1 = sigmoid(zx) * tanh(hx); global row 0 forced to 0.
// Operates on rows*H elements of a chunk whose global row offset is grow0.
// ---------------------------------------------------------------------------
__global__ __launch_bounds__(256) void step0_kernel(
    const float* __restrict__ zx, const float* __restrict__ hx,
    float* __restrict__ hout, long total, int grow0)
{
    long i = ((long)blockIdx.x * blockDim.x + threadIdx.x) * 4;
    if (i >= total) return;
    const float4 z4 = *(const float4*)(zx + i);
    const float4 h4 = *(const float4*)(hx + i);
    float4 o;
    o.x = fsigmoid(z4.x) * ftanh(h4.x);
    o.y = fsigmoid(z4.y) * ftanh(h4.y);
    o.z = fsigmoid(z4.z) * ftanh(h4.z);
    o.w = fsigmoid(z4.w) * ftanh(h4.w);
    if (grow0 == 0 && i < H) o = make_float4(0.f, 0.f, 0.f, 0.f);
    *(float4*)(hout + i) = o;
}

// ---------------------------------------------------------------------------
// Edge gather for a chunk of cc edges (pointers pre-offset to chunk):
//   smh[e] = sum_n h[bg[e,n]]
//   smg[e] = sum_n sigmoid(rx[e] + g[bg[e,n]] + b_ur) * h[bg[e,n]]
// h, g are FULL arrays; rx/bg/smh/smg are chunk-local. 64 lanes per edge.
// ---------------------------------------------------------------------------
__global__ __launch_bounds__(256) void edge_kernel(
    const float* __restrict__ h, const float* __restrict__ g,
    const float* __restrict__ rx, const float* __restrict__ b_ur,
    const int* __restrict__ bgraph,
    float* __restrict__ smh, float* __restrict__ smg, int cc)
{
    const int e = blockIdx.x * 4 + (threadIdx.x >> 6);
    if (e >= cc) return;
    const int j = (threadIdx.x & 63) << 2;
    const float4 rv = *(const float4*)(rx + (size_t)e * H + j);
    const float4 bu = *(const float4*)(b_ur + j);
    float4 sh = make_float4(0.f, 0.f, 0.f, 0.f);
    float4 sg = make_float4(0.f, 0.f, 0.f, 0.f);
#pragma unroll
    for (int n = 0; n < NB; n++) {
        const int idx = bgraph[e * NB + n];
        const float4 hv = *(const float4*)(h + (size_t)idx * H + j);
        const float4 gv = *(const float4*)(g + (size_t)idx * H + j);
        sh.x += hv.x; sh.y += hv.y; sh.z += hv.z; sh.w += hv.w;
        float r;
        r = fsigmoid(rv.x + gv.x + bu.x); sg.x = fmaf(r, hv.x, sg.x);
        r = fsigmoid(rv.y + gv.y + bu.y); sg.y = fmaf(r, hv.y, sg.y);
        r = fsigmoid(rv.z + gv.z + bu.z); sg.z = fmaf(r, hv.z, sg.z);
        r = fsigmoid(rv.w + gv.w + bu.w); sg.w = fmaf(r, hv.w, sg.w);
    }
    *(float4*)(smh + (size_t)e * H + j) = sh;
    *(float4*)(smg + (size_t)e * H + j) = sg;
}

// ---------------------------------------------------------------------------
// GRU update for a chunk of M rows (row-local pointers; grow0 = global offset).
// FUSED_X=false: tz = smh@W_z[128:384]; th = smg@W_h[128:384];
//                z = sig(zx + tz); pre = tanh(hx + th)   (zb=zx, hb=hx chunks)
// FUSED_X=true:  tz = Xc@W_z[0:128] + smh@W_z[128:384] (+b_z via zb);
//                th = Xc@W_h[0:128] + smg@W_h[128:384] (+b_h via hb)
// h_new = (1-z)*smh + z*pre; global row 0 forced to 0.
// ---------------------------------------------------------------------------
template<bool FUSED_X>
__global__ __launch_bounds__(256) void update_kernel(
    const float* __restrict__ Xc,
    const float* __restrict__ smh, const float* __restrict__ smg,
    const float* __restrict__ W_z, const float* __restrict__ W_h,
    const float* __restrict__ zb, const float* __restrict__ hb,
    float* __restrict__ hout, int M, int grow0)
{
    __shared__ float As1[BK][BM + 4];
    __shared__ float As2[BK][BM + 4];
    __shared__ float Bs1[BK][BN];
    __shared__ float Bs2[BK][BN];

    const int tid = threadIdx.x;
    const int m0 = blockIdx.x * BM;
    const int n0 = blockIdx.y * BN;
    const int ty = tid >> 4;
    const int tx = tid & 15;
    const int lar = tid >> 2;
    const int lac = (tid & 3) << 2;
    const int lbr = tid >> 4;
    const int lbc = (tid & 15) << 2;

    float4 accz[8], acch[8];
#pragma unroll
    for (int i = 0; i < 8; i++) {
        accz[i] = make_float4(0.f, 0.f, 0.f, 0.f);
        acch[i] = make_float4(0.f, 0.f, 0.f, 0.f);
    }

    if (FUSED_X) {
        // Phase 1: K = 0..127, A = Xc [M,128], B = W_z/W_h rows 0..127
        for (int k0 = 0; k0 < IN_DIM; k0 += BK) {
            const int r0 = m0 + lar, r1 = r0 + 64;
            float4 a0 = make_float4(0.f,0.f,0.f,0.f), a1 = a0;
            if (r0 < M) a0 = *(const float4*)(Xc + (size_t)r0 * IN_DIM + k0 + lac);
            if (r1 < M) a1 = *(const float4*)(Xc + (size_t)r1 * IN_DIM + k0 + lac);
            const float4 b1 = *(const float4*)(W_z + (size_t)(k0 + lbr) * H + n0 + lbc);
            const float4 b2 = *(const float4*)(W_h + (size_t)(k0 + lbr) * H + n0 + lbc);

            As1[lac + 0][lar] = a0.x; As1[lac + 1][lar] = a0.y;
            As1[lac + 2][lar] = a0.z; As1[lac + 3][lar] = a0.w;
            As1[lac + 0][lar + 64] = a1.x; As1[lac + 1][lar + 64] = a1.y;
            As1[lac + 2][lar + 64] = a1.z; As1[lac + 3][lar + 64] = a1.w;
            *(float4*)&Bs1[lbr][lbc] = b1;
            *(float4*)&Bs2[lbr][lbc] = b2;
            __syncthreads();

#pragma unroll
            for (int k = 0; k < BK; k++) {
                const float4 bz = *(const float4*)&Bs1[k][tx << 2];
                const float4 bh = *(const float4*)&Bs2[k][tx << 2];
                const float4 alo = *(const float4*)&As1[k][ty << 3];
                const float4 ahi = *(const float4*)&As1[k][(ty << 3) + 4];
                const float av[8] = {alo.x, alo.y, alo.z, alo.w, ahi.x, ahi.y, ahi.z, ahi.w};
#pragma unroll
                for (int i = 0; i < 8; i++) {
                    accz[i].x = fmaf(av[i], bz.x, accz[i].x);
                    accz[i].y = fmaf(av[i], bz.y, accz[i].y);
                    accz[i].z = fmaf(av[i], bz.z, accz[i].z);
                    accz[i].w = fmaf(av[i], bz.w, accz[i].w);
                    acch[i].x = fmaf(av[i], bh.x, acch[i].x);
                    acch[i].y = fmaf(av[i], bh.y, acch[i].y);
                    acch[i].z = fmaf(av[i], bh.z, acch[i].z);
                    acch[i].w = fmaf(av[i], bh.w, acch[i].w);
                }
            }
            __syncthreads();
        }
    }

    // Phase 2: K over hidden dim, A1 = smh, A2 = smg, B rows 128..383
    for (int k0 = 0; k0 < H; k0 += BK) {
        const int r0 = m0 + lar, r1 = r0 + 64;
        float4 a0 = make_float4(0.f,0.f,0.f,0.f), a1 = a0, c0 = a0, c1 = a0;
        if (r0 < M) {
            a0 = *(const float4*)(smh + (size_t)r0 * H + k0 + lac);
            c0 = *(const float4*)(smg + (size_t)r0 * H + k0 + lac);
        }
        if (r1 < M) {
            a1 = *(const float4*)(smh + (size_t)r1 * H + k0 + lac);
            c1 = *(const float4*)(smg + (size_t)r1 * H + k0 + lac);
        }
        const float4 b1 = *(const float4*)(W_z + (size_t)(IN_DIM + k0 + lbr) * H + n0 + lbc);
        const float4 b2 = *(const float4*)(W_h + (size_t)(IN_DIM + k0 + lbr) * H + n0 + lbc);

        As1[lac + 0][lar] = a0.x; As1[lac + 1][lar] = a0.y;
        As1[lac + 2][lar] = a0.z; As1[lac + 3][lar] = a0.w;
        As1[lac + 0][lar + 64] = a1.x; As1[lac + 1][lar + 64] = a1.y;
        As1[lac + 2][lar + 64] = a1.z; As1[lac + 3][lar + 64] = a1.w;
        As2[lac + 0][lar] = c0.x; As2[lac + 1][lar] = c0.y;
        As2[lac + 2][lar] = c0.z; As2[lac + 3][lar] = c0.w;
        As2[lac + 0][lar + 64] = c1.x; As2[lac + 1][lar + 64] = c1.y;
        As2[lac + 2][lar + 64] = c1.z; As2[lac + 3][lar + 64] = c1.w;
        *(float4*)&Bs1[lbr][lbc] = b1;
        *(float4*)&Bs2[lbr][lbc] = b2;
        __syncthreads();

#pragma unroll
        for (int k = 0; k < BK; k++) {
            const float4 bz = *(const float4*)&Bs1[k][tx << 2];
            const float4 bh = *(const float4*)&Bs2[k][tx << 2];
            const float4 alo = *(const float4*)&As1[k][ty << 3];
            const float4 ahi = *(const float4*)&As1[k][(ty << 3) + 4];
            const float4 clo = *(const float4*)&As2[k][ty << 3];
            const float4 chi = *(const float4*)&As2[k][(ty << 3) + 4];
            const float av[8] = {alo.x, alo.y, alo.z, alo.w, ahi.x, ahi.y, ahi.z, ahi.w};
            const float cv[8] = {clo.x, clo.y, clo.z, clo.w, chi.x, chi.y, chi.z, chi.w};
#pragma unroll
            for (int i = 0; i < 8; i++) {
                accz[i].x = fmaf(av[i], bz.x, accz[i].x);
                accz[i].y = fmaf(av[i], bz.y, accz[i].y);
                accz[i].z = fmaf(av[i], bz.z, accz[i].z);
                accz[i].w = fmaf(av[i], bz.w, accz[i].w);
                acch[i].x = fmaf(cv[i], bh.x, acch[i].x);
                acch[i].y = fmaf(cv[i], bh.y, acch[i].y);
                acch[i].z = fmaf(cv[i], bh.z, acch[i].z);
                acch[i].w = fmaf(cv[i], bh.w, acch[i].w);
            }
        }
        __syncthreads();
    }

    float4 zbias = make_float4(0.f,0.f,0.f,0.f), hbias = zbias;
    if (FUSED_X) {
        zbias = *(const float4*)(zb + n0 + (tx << 2));
        hbias = *(const float4*)(hb + n0 + (tx << 2));
    }
#pragma unroll
    for (int i = 0; i < 8; i++) {
        const int row = m0 + (ty << 3) + i;
        if (row >= M) continue;
        const size_t off = (size_t)row * H + n0 + (tx << 2);
        float4 zadd, hadd;
        if (FUSED_X) { zadd = zbias; hadd = hbias; }
        else {
            zadd = *(const float4*)(zb + off);
            hadd = *(const float4*)(hb + off);
        }
        const float4 shv = *(const float4*)(smh + off);
        float4 o;
        {
            float z = fsigmoid(zadd.x + accz[i].x);
            float p = ftanh(hadd.x + acch[i].x);
            o.x = (1.f - z) * shv.x + z * p;
            z = fsigmoid(zadd.y + accz[i].y);
            p = ftanh(hadd.y + acch[i].y);
            o.y = (1.f - z) * shv.y + z * p;
            z = fsigmoid(zadd.z + accz[i].z);
            p = ftanh(hadd.z + acch[i].z);
            o.z = (1.f - z) * shv.z + z * p;
            z = fsigmoid(zadd.w + accz[i].w);
            p = ftanh(hadd.w + acch[i].w);
            o.w = (1.f - z) * shv.w + z * p;
        }
        if (grow0 + row == 0) o = make_float4(0.f, 0.f, 0.f, 0.f);
        *(float4*)(hout + off) = o;
    }
}

// ---------------------------------------------------------------------------
// Node gather: nei[v] = sum_n h[agraph[v,n]]
// ---------------------------------------------------------------------------
__global__ __launch_bounds__(256) void node_gather_kernel(
    const float* __restrict__ hmsg, const int* __restrict__ agraph,
    float* __restrict__ nei, int N)
{
    const int v = blockIdx.x * 4 + (threadIdx.x >> 6);
    if (v >= N) return;
    const int j = (threadIdx.x & 63) << 2;
    float4 s = make_float4(0.f, 0.f, 0.f, 0.f);
#pragma unroll
    for (int n = 0; n < NB; n++) {
        const int idx = agraph[v * NB + n];
        const float4 hv = *(const float4*)(hmsg + (size_t)idx * H + j);
        s.x += hv.x; s.y += hv.y; s.z += hv.z; s.w += hv.w;
    }
    *(float4*)(nei + (size_t)v * H + j) = s;
}

// ---------------------------------------------------------------------------
// Node GEMM: out = relu(fnode@Wo[0:128] + nei@Wo[128:384] + b_o) * mask
// ---------------------------------------------------------------------------
__global__ __launch_bounds__(256) void node_gemm_kernel(
    const float* __restrict__ A1, const float* __restrict__ A2,
    const float* __restrict__ B,
    const float* __restrict__ bias, const float* __restrict__ mask,
    float* __restrict__ C, int M)
{
    __shared__ float As[BK][BM + 4];
    __shared__ float Bs[BK][BN];

    const int tid = threadIdx.x;
    const int m0 = blockIdx.x * BM;
    const int n0 = blockIdx.y * BN;
    const int ty = tid >> 4;
    const int tx = tid & 15;
    const int lar = tid >> 2;
    const int lac = (tid & 3) << 2;
    const int lbr = tid >> 4;
    const int lbc = (tid & 15) << 2;

    float4 acc[8];
#pragma unroll
    for (int i = 0; i < 8; i++) acc[i] = make_float4(0.f, 0.f, 0.f, 0.f);

    for (int k0 = 0; k0 < IN_DIM + H; k0 += BK) {
        const float* Asrc;
        int lda, kk;
        if (k0 < IN_DIM) { Asrc = A1; lda = IN_DIM; kk = k0; }
        else             { Asrc = A2; lda = H;      kk = k0 - IN_DIM; }
        const int r0 = m0 + lar, r1 = r0 + 64;
        float4 a0 = make_float4(0.f,0.f,0.f,0.f), a1 = a0;
        if (r0 < M) a0 = *(const float4*)(Asrc + (size_t)r0 * lda + kk + lac);
        if (r1 < M) a1 = *(const float4*)(Asrc + (size_t)r1 * lda + kk + lac);
        const float4 b = *(const float4*)(B + (size_t)(k0 + lbr) * H + n0 + lbc);

        As[lac + 0][lar] = a0.x; As[lac + 1][lar] = a0.y;
        As[lac + 2][lar] = a0.z; As[lac + 3][lar] = a0.w;
        As[lac + 0][lar + 64] = a1.x; As[lac + 1][lar + 64] = a1.y;
        As[lac + 2][lar + 64] = a1.z; As[lac + 3][lar + 64] = a1.w;
        *(float4*)&Bs[lbr][lbc] = b;
        __syncthreads();

#pragma unroll
        for (int k = 0; k < BK; k++) {
            const float4 bv = *(const float4*)&Bs[k][tx << 2];
            const float4 alo = *(const float4*)&As[k][ty << 3];
            const float4 ahi = *(const float4*)&As[k][(ty << 3) + 4];
            const float av[8] = {alo.x, alo.y, alo.z, alo.w, ahi.x, ahi.y, ahi.z, ahi.w};
#pragma unroll
            for (int i = 0; i < 8; i++) {
                acc[i].x = fmaf(av[i], bv.x, acc[i].x);
                acc[i].y = fmaf(av[i], bv.y, acc[i].y);
                acc[i].z = fmaf(av[i], bv.z, acc[i].z);
                acc[i].w = fmaf(av[i], bv.w, acc[i].w);
            }
        }
        __syncthreads();
    }

    const float4 bv = *(const float4*)(bias + n0 + (tx << 2));
#pragma unroll
    for (int i = 0; i < 8; i++) {
        const int row = m0 + (ty << 3) + i;
        if (row >= M) continue;
        const float mk = mask[row];
        float4 o = acc[i];
        o.x = fmaxf(o.x + bv.x, 0.f) * mk;
        o.y = fmaxf(o.y + bv.y, 0.f) * mk;
        o.z = fmaxf(o.z + bv.z, 0.f) * mk;
        o.w = fmaxf(o.w + bv.w, 0.f) * mk;
        *(float4*)(C + (size_t)row * H + n0 + (tx << 2)) = o;
    }
}

// ---------------------------------------------------------------------------
extern "C" void kernel_launch(void* const* d_in, const int* in_sizes, int n_in,
                              void* d_out, int out_size, void* d_ws, size_t ws_size,
                              hipStream_t stream)
{
    const float* fnode  = (const float*)d_in[0];
    const float* fmess  = (const float*)d_in[1];
    const int*   agraph = (const int*)  d_in[2];
    const int*   bgraph = (const int*)  d_in[3];
    const float* mask   = (const float*)d_in[4];
    const float* W_z    = (const float*)d_in[5];
    const float* b_z    = (const float*)d_in[6];
    const float* W_r    = (const float*)d_in[7];
    const float* U_r    = (const float*)d_in[8];
    const float* b_ur   = (const float*)d_in[9];
    const float* W_h    = (const float*)d_in[10];
    const float* b_h    = (const float*)d_in[11];
    const float* W_o    = (const float*)d_in[12];
    const float* b_o    = (const float*)d_in[13];

    const int N = in_sizes[0] / IN_DIM;   // 35000
    const int E = in_sizes[1] / IN_DIM;   // 80000
    const size_t EHf = (size_t)E * H;

    float* out_nodes = (float*)d_out;                   // [N,H]
    float* hA = (float*)d_out + (size_t)N * H;          // [E,H], final h lives here
    float* ws = (float*)d_ws;
    const size_t avail = ws_size / sizeof(float);

    const dim3 blk(256);
    #define GGRID(M) dim3(((M) + BM - 1) / BM, H / BN)

    if (avail >= 6 * EHf) {
        // ---- Tier 1: full precompute (needs 492 MB ws) ----
        float* g   = ws;
        float* rx  = ws + 1 * EHf;
        float* zx  = ws + 2 * EHf;
        float* hx  = ws + 3 * EHf;
        float* smh = ws + 4 * EHf;
        float* smg = ws + 5 * EHf;

        gemm_kernel<false><<<GGRID(E), blk, 0, stream>>>(fmess, W_r, nullptr, rx, E, IN_DIM);
        gemm_kernel<true ><<<GGRID(E), blk, 0, stream>>>(fmess, W_z, b_z,     zx, E, IN_DIM);
        gemm_kernel<true ><<<GGRID(E), blk, 0, stream>>>(fmess, W_h, b_h,     hx, E, IN_DIM);
        step0_kernel<<<(int)((EHf / 4 + 255) / 256), blk, 0, stream>>>(zx, hx, hA, (long)EHf, 0);

        for (int t = 1; t < 5; t++) {
            gemm_kernel<false><<<GGRID(E), blk, 0, stream>>>(hA, U_r, nullptr, g, E, H);
            edge_kernel<<<(E + 3) / 4, blk, 0, stream>>>(hA, g, rx, b_ur, bgraph, smh, smg, E);
            update_kernel<false><<<GGRID(E), blk, 0, stream>>>(
                nullptr, smh, smg, W_z, W_h, zx, hx, hA, E, 0);
        }
        node_gather_kernel<<<(N + 3) / 4, blk, 0, stream>>>(hA, agraph, g, N);
        node_gemm_kernel<<<GGRID(N), blk, 0, stream>>>(fnode, g, W_o, b_o, mask, out_nodes, N);

    } else if (avail >= 3 * EHf + (size_t)BM * H) {
        // ---- Tier 3: full smh/smg, fused-X updates, chunked rx (needs 247 MB) ----
        float* g   = ws;
        float* smh = ws + 1 * EHf;
        float* smg = ws + 2 * EHf;
        float* rxc = ws + 3 * EHf;
        size_t CHr = (avail - 3 * EHf) / H;
        if (CHr > (size_t)E) CHr = (size_t)E;
        CHr = (CHr / BM) * BM;

        // step0: borrow smh/smg as zx/hx
        gemm_kernel<true><<<GGRID(E), blk, 0, stream>>>(fmess, W_z, b_z, smh, E, IN_DIM);
        gemm_kernel<true><<<GGRID(E), blk, 0, stream>>>(fmess, W_h, b_h, smg, E, IN_DIM);
        step0_kernel<<<(int)((EHf / 4 + 255) / 256), blk, 0, stream>>>(smh, smg, hA, (long)EHf, 0);

        for (int t = 1; t < 5; t++) {
            gemm_kernel<false><<<GGRID(E), blk, 0, stream>>>(hA, U_r, nullptr, g, E, H);
            for (int c0 = 0; c0 < E; c0 += (int)CHr) {
                const int cc = (E - c0 < (int)CHr) ? (E - c0) : (int)CHr;
                gemm_kernel<false><<<GGRID(cc), blk, 0, stream>>>(
                    fmess + (size_t)c0 * IN_DIM, W_r, nullptr, rxc, cc, IN_DIM);
                edge_kernel<<<(cc + 3) / 4, blk, 0, stream>>>(
                    hA, g, rxc, b_ur, bgraph + (size_t)c0 * NB,
                    smh + (size_t)c0 * H, smg + (size_t)c0 * H, cc);
            }
            update_kernel<true><<<GGRID(E), blk, 0, stream>>>(
                fmess, smh, smg, W_z, W_h, b_z, b_h, hA, E, 0);
        }
        node_gather_kernel<<<(N + 3) / 4, blk, 0, stream>>>(hA, agraph, g, N);
        node_gemm_kernel<<<GGRID(N), blk, 0, stream>>>(fnode, g, W_o, b_o, mask, out_nodes, N);

    } else {
        // ---- Tier 4: minimal ws (2*EH = 164 MB); chunk bufs live in out_nodes ----
        float* g  = ws;
        float* hB = ws + 1 * EHf;
        const int CH = ((N / 3) / BM) * BM;            // 11648 for N=35000
        float* smh = out_nodes;
        float* smg = out_nodes + (size_t)CH * H;
        float* rxc = out_nodes + 2 * (size_t)CH * H;

        for (int c0 = 0; c0 < E; c0 += CH) {
            const int cc = (E - c0 < CH) ? (E - c0) : CH;
            const long tot = (long)cc * H;
            gemm_kernel<true><<<GGRID(cc), blk, 0, stream>>>(
                fmess + (size_t)c0 * IN_DIM, W_z, b_z, smh, cc, IN_DIM);
            gemm_kernel<true><<<GGRID(cc), blk, 0, stream>>>(
                fmess + (size_t)c0 * IN_DIM, W_h, b_h, smg, cc, IN_DIM);
            step0_kernel<<<(int)((tot / 4 + 255) / 256), blk, 0, stream>>>(
                smh, smg, hA + (size_t)c0 * H, tot, c0);
        }
        float* hold = hA;
        float* hnew = hB;
        for (int t = 1; t < 5; t++) {
            gemm_kernel<false><<<GGRID(E), blk, 0, stream>>>(hold, U_r, nullptr, g, E, H);
            for (int c0 = 0; c0 < E; c0 += CH) {
                const int cc = (E - c0 < CH) ? (E - c0) : CH;
                gemm_kernel<false><<<GGRID(cc), blk, 0, stream>>>(
                    fmess + (size_t)c0 * IN_DIM, W_r, nullptr, rxc, cc, IN_DIM);
                edge_kernel<<<(cc + 3) / 4, blk, 0, stream>>>(
                    hold, g, rxc, b_ur, bgraph + (size_t)c0 * NB, smh, smg, cc);
                update_kernel<true><<<GGRID(cc), blk, 0, stream>>>(
                    fmess + (size_t)c0 * IN_DIM, smh, smg, W_z, W_h, b_z, b_h,
                    hnew + (size_t)c0 * H, cc, c0);
            }
            float* tmp = hold; hold = hnew; hnew = tmp;
        }
        // after 4 swaps, final h is back in hA (d_out)
        node_gather_kernel<<<(N + 3) / 4, blk, 0, stream>>>(hA, agraph, g, N);
        node_gemm_kernel<<<GGRID(N), blk, 0, stream>>>(fnode, g, W_o, b_o, mask, out_nodes, N);
    }
    #undef GGRID
}

// Round 4
// 2220.590 us; speedup vs baseline: 1.7366x; 1.7366x over previous
//
#include <hip/hip_runtime.h>

#define H 256
#define NB 6
#define IN_DIM 128

typedef short s8v __attribute__((ext_vector_type(8)));
typedef float f4v __attribute__((ext_vector_type(4)));

__device__ __forceinline__ float fsigmoid(float x) {
    return 1.0f / (1.0f + __expf(-x));
}
__device__ __forceinline__ float ftanh(float x) {
    x = fminf(15.0f, fmaxf(-15.0f, x));
    float e = __expf(2.0f * x);
    return (e - 1.0f) / (e + 1.0f);
}
// fp32 -> bf16 RNE, no API dependence
__device__ __forceinline__ unsigned short f2bf(float x) {
    unsigned u = __float_as_uint(x);
    u += 0x7fffu + ((u >> 16) & 1u);
    return (unsigned short)(u >> 16);
}
__device__ __forceinline__ float bf2f(unsigned short b) {
    return __uint_as_float(((unsigned)b) << 16);
}

// ---------------------------------------------------------------------------
// Weight convert+transpose: W [K][256] fp32 -> WT_hi/WT_lo [256][K] bf16.
// Tiny; runs once per launch.
// ---------------------------------------------------------------------------
__global__ __launch_bounds__(256) void wconv_kernel(
    const float* __restrict__ W, unsigned short* __restrict__ hi,
    unsigned short* __restrict__ lo, int K)
{
    const int i = blockIdx.x * 256 + threadIdx.x;   // i = n*K + k
    if (i >= K * 256) return;
    const int n = i / K, k = i - n * K;
    const float x = W[(size_t)k * H + n];
    const unsigned short h = f2bf(x);
    hi[i] = h;
    lo[i] = f2bf(x - bf2f(h));
}

// ---------------------------------------------------------------------------
// Split-bf16 MFMA GEMM: C[M,256] = concat(A1[M,K1], A2[M,K2]) @ B[KT,256]
// B pre-split/transposed planes BThi/BTlo [256][KT] bf16.
// BM=128, BN=128, grid=(ceil(M/128), 2). 256 thr = 4 waves (2x2), wave=64x64.
// EPI: 0 = plain store; 1 = relu(acc+bias)*mask[row].
// fp32 A is split hi/lo during LDS staging; 3 MFMAs per fragment product.
// ---------------------------------------------------------------------------
template<int EPI>
__global__ __launch_bounds__(256, 2) void mfma_gemm_kernel(
    const float* __restrict__ A1, int K1,
    const float* __restrict__ A2, int K2,
    const unsigned short* __restrict__ BThi, const unsigned short* __restrict__ BTlo,
    const float* __restrict__ bias, const float* __restrict__ mask,
    float* __restrict__ C, int M)
{
    const int KT = K1 + K2;
    __shared__ __align__(16) unsigned short Ah[128 * 40];
    __shared__ __align__(16) unsigned short Al[128 * 40];
    __shared__ __align__(16) unsigned short Bh[128 * 40];
    __shared__ __align__(16) unsigned short Bl[128 * 40];

    const int tid = threadIdx.x;
    const int m0 = blockIdx.x * 128, n0 = blockIdx.y * 128;
    const int lane = tid & 63;
    const int w = tid >> 6;
    const int wmb = (w >> 1) * 64, wnb = (w & 1) * 64;
    const int lr = lane & 15;
    const int lkb = (lane >> 4) * 8;     // k-offset (ushorts) of this lane's frag
    const int drb = (lane >> 4) * 4;     // D row base within 16x16 frag
    const int ar = tid >> 1, kh = (tid & 1) * 16;   // staging: row / k-half

    f4v acc[4][4];
#pragma unroll
    for (int mi = 0; mi < 4; mi++)
#pragma unroll
        for (int ni = 0; ni < 4; ni++) acc[mi][ni] = (f4v){0.f, 0.f, 0.f, 0.f};

    for (int k0 = 0; k0 < KT; k0 += 32) {
        const float* Asrc; int lda, kk;
        if (k0 < K1) { Asrc = A1; lda = K1; kk = k0; }
        else         { Asrc = A2; lda = K2; kk = k0 - K1; }
        const int grow = m0 + ar;
        if (grow < M) {
            const float* p = Asrc + (size_t)grow * lda + kk + kh;
#pragma unroll
            for (int i = 0; i < 4; i++) {
                const float4 v = *(const float4*)(p + 4 * i);
                const unsigned short hx = f2bf(v.x), hy = f2bf(v.y),
                                     hz = f2bf(v.z), hw = f2bf(v.w);
                const ushort4 hv = make_ushort4(hx, hy, hz, hw);
                const ushort4 lv = make_ushort4(
                    f2bf(v.x - bf2f(hx)), f2bf(v.y - bf2f(hy)),
                    f2bf(v.z - bf2f(hz)), f2bf(v.w - bf2f(hw)));
                *(ushort4*)&Ah[ar * 40 + kh + 4 * i] = hv;
                *(ushort4*)&Al[ar * 40 + kh + 4 * i] = lv;
            }
        }
        {
            // B tile: each thread stages 16 ushorts per plane (full k coverage:
            // 2 threads/row x 16 = 32).  [Round-3 bug: only 8 were staged.]
            const size_t bo = (size_t)(n0 + ar) * KT + k0 + kh;
            *(s8v*)&Bh[ar * 40 + kh]     = *(const s8v*)(BThi + bo);
            *(s8v*)&Bh[ar * 40 + kh + 8] = *(const s8v*)(BThi + bo + 8);
            *(s8v*)&Bl[ar * 40 + kh]     = *(const s8v*)(BTlo + bo);
            *(s8v*)&Bl[ar * 40 + kh + 8] = *(const s8v*)(BTlo + bo + 8);
        }
        __syncthreads();

        s8v av[4], aw[4];
#pragma unroll
        for (int mi = 0; mi < 4; mi++) {
            const int rr = (wmb + mi * 16 + lr) * 40 + lkb;
            av[mi] = *(const s8v*)&Ah[rr];
            aw[mi] = *(const s8v*)&Al[rr];
        }
#pragma unroll
        for (int ni = 0; ni < 4; ni++) {
            const int cc = (wnb + ni * 16 + lr) * 40 + lkb;
            const s8v bv = *(const s8v*)&Bh[cc];
            const s8v bw = *(const s8v*)&Bl[cc];
#pragma unroll
            for (int mi = 0; mi < 4; mi++) {
                acc[mi][ni] = __builtin_amdgcn_mfma_f32_16x16x32_bf16(av[mi], bv, acc[mi][ni], 0, 0, 0);
                acc[mi][ni] = __builtin_amdgcn_mfma_f32_16x16x32_bf16(av[mi], bw, acc[mi][ni], 0, 0, 0);
                acc[mi][ni] = __builtin_amdgcn_mfma_f32_16x16x32_bf16(aw[mi], bv, acc[mi][ni], 0, 0, 0);
            }
        }
        __syncthreads();
    }

#pragma unroll
    for (int mi = 0; mi < 4; mi++) {
#pragma unroll
        for (int ni = 0; ni < 4; ni++) {
#pragma unroll
            for (int r = 0; r < 4; r++) {
                const int row = m0 + wmb + mi * 16 + drb + r;
                if (row >= M) continue;
                const int col = n0 + wnb + ni * 16 + lr;
                float v = acc[mi][ni][r];
                if (EPI == 1) v = fmaxf(v + bias[col], 0.f) * mask[row];
                C[(size_t)row * H + col] = v;
            }
        }
    }
}

// ---------------------------------------------------------------------------
// GRU update, dual split-bf16 MFMA GEMM with fused X-term (K = 128 + 256):
//   accz = Xc@Wz[0:128] (+ smh@Wz[128:384] if !STEP0)
//   acch = Xc@Wh[0:128] (+ smg@Wh[128:384] if !STEP0)
//   z = sig(accz + b_z); p = tanh(acch + b_h)
//   h = STEP0 ? z*p : (1-z)*smh + z*p ;  global row 0 -> 0
// BM=128, BN=64, grid=(ceil(M/128),4). 4 waves 2x2, wave tile 64x32.
// ---------------------------------------------------------------------------
template<bool STEP0>
__global__ __launch_bounds__(256, 2) void mfma_update_kernel(
    const float* __restrict__ Xc,
    const float* __restrict__ smh, const float* __restrict__ smg,
    const unsigned short* __restrict__ WzThi, const unsigned short* __restrict__ WzTlo,
    const unsigned short* __restrict__ WhThi, const unsigned short* __restrict__ WhTlo,
    const float* __restrict__ b_z, const float* __restrict__ b_h,
    float* __restrict__ hout, int M, int grow0)
{
    __shared__ __align__(16) unsigned short Ah[128 * 40];
    __shared__ __align__(16) unsigned short Al[128 * 40];
    __shared__ __align__(16) unsigned short Ch[128 * 40];
    __shared__ __align__(16) unsigned short Cl[128 * 40];
    __shared__ __align__(16) unsigned short Bzh[64 * 40];
    __shared__ __align__(16) unsigned short Bzl[64 * 40];
    __shared__ __align__(16) unsigned short Bhh[64 * 40];
    __shared__ __align__(16) unsigned short Bhl[64 * 40];

    const int tid = threadIdx.x;
    const int m0 = blockIdx.x * 128, n0 = blockIdx.y * 64;
    const int lane = tid & 63;
    const int w = tid >> 6;
    const int wmb = (w >> 1) * 64, wnb = (w & 1) * 32;
    const int lr = lane & 15;
    const int lkb = (lane >> 4) * 8;
    const int drb = (lane >> 4) * 4;
    const int ar = tid >> 1, kh = (tid & 1) * 16;   // A staging (128 rows)
    const int bc = tid >> 2, kq = (tid & 3) * 8;    // B staging (64 cols)

    f4v accz[4][2], acch[4][2];
#pragma unroll
    for (int mi = 0; mi < 4; mi++)
#pragma unroll
        for (int ni = 0; ni < 2; ni++) {
            accz[mi][ni] = (f4v){0.f, 0.f, 0.f, 0.f};
            acch[mi][ni] = (f4v){0.f, 0.f, 0.f, 0.f};
        }

    // ---- Phase X: K = 0..127 over Xc (feeds BOTH accz and acch) ----
    for (int k0 = 0; k0 < IN_DIM; k0 += 32) {
        const int grow = m0 + ar;
        if (grow < M) {
            const float* p = Xc + (size_t)grow * IN_DIM + k0 + kh;
#pragma unroll
            for (int i = 0; i < 4; i++) {
                const float4 v = *(const float4*)(p + 4 * i);
                const unsigned short hx = f2bf(v.x), hy = f2bf(v.y),
                                     hz = f2bf(v.z), hw = f2bf(v.w);
                *(ushort4*)&Ah[ar * 40 + kh + 4 * i] = make_ushort4(hx, hy, hz, hw);
                *(ushort4*)&Al[ar * 40 + kh + 4 * i] = make_ushort4(
                    f2bf(v.x - bf2f(hx)), f2bf(v.y - bf2f(hy)),
                    f2bf(v.z - bf2f(hz)), f2bf(v.w - bf2f(hw)));
            }
        }
        {
            const size_t bo = (size_t)(n0 + bc) * 384 + k0 + kq;
            *(s8v*)&Bzh[bc * 40 + kq] = *(const s8v*)(WzThi + bo);
            *(s8v*)&Bzl[bc * 40 + kq] = *(const s8v*)(WzTlo + bo);
            *(s8v*)&Bhh[bc * 40 + kq] = *(const s8v*)(WhThi + bo);
            *(s8v*)&Bhl[bc * 40 + kq] = *(const s8v*)(WhTlo + bo);
        }
        __syncthreads();

        s8v av[4], aw[4];
#pragma unroll
        for (int mi = 0; mi < 4; mi++) {
            const int rr = (wmb + mi * 16 + lr) * 40 + lkb;
            av[mi] = *(const s8v*)&Ah[rr];
            aw[mi] = *(const s8v*)&Al[rr];
        }
#pragma unroll
        for (int ni = 0; ni < 2; ni++) {
            const int cc = (wnb + ni * 16 + lr) * 40 + lkb;
            const s8v bzv = *(const s8v*)&Bzh[cc];
            const s8v bzw = *(const s8v*)&Bzl[cc];
            const s8v bhv = *(const s8v*)&Bhh[cc];
            const s8v bhw = *(const s8v*)&Bhl[cc];
#pragma unroll
            for (int mi = 0; mi < 4; mi++) {
                accz[mi][ni] = __builtin_amdgcn_mfma_f32_16x16x32_bf16(av[mi], bzv, accz[mi][ni], 0, 0, 0);
                accz[mi][ni] = __builtin_amdgcn_mfma_f32_16x16x32_bf16(av[mi], bzw, accz[mi][ni], 0, 0, 0);
                accz[mi][ni] = __builtin_amdgcn_mfma_f32_16x16x32_bf16(aw[mi], bzv, accz[mi][ni], 0, 0, 0);
                acch[mi][ni] = __builtin_amdgcn_mfma_f32_16x16x32_bf16(av[mi], bhv, acch[mi][ni], 0, 0, 0);
                acch[mi][ni] = __builtin_amdgcn_mfma_f32_16x16x32_bf16(av[mi], bhw, acch[mi][ni], 0, 0, 0);
                acch[mi][ni] = __builtin_amdgcn_mfma_f32_16x16x32_bf16(aw[mi], bhv, acch[mi][ni], 0, 0, 0);
            }
        }
        __syncthreads();
    }

    // ---- Phase H: K = 128..383; accz <- smh, acch <- smg ----
    if (!STEP0) {
        for (int k0 = 0; k0 < H; k0 += 32) {
            const int grow = m0 + ar;
            if (grow < M) {
                const float* p1 = smh + (size_t)grow * H + k0 + kh;
                const float* p2 = smg + (size_t)grow * H + k0 + kh;
#pragma unroll
                for (int i = 0; i < 4; i++) {
                    const float4 v = *(const float4*)(p1 + 4 * i);
                    const unsigned short hx = f2bf(v.x), hy = f2bf(v.y),
                                         hz = f2bf(v.z), hw = f2bf(v.w);
                    *(ushort4*)&Ah[ar * 40 + kh + 4 * i] = make_ushort4(hx, hy, hz, hw);
                    *(ushort4*)&Al[ar * 40 + kh + 4 * i] = make_ushort4(
                        f2bf(v.x - bf2f(hx)), f2bf(v.y - bf2f(hy)),
                        f2bf(v.z - bf2f(hz)), f2bf(v.w - bf2f(hw)));
                    const float4 u = *(const float4*)(p2 + 4 * i);
                    const unsigned short gx = f2bf(u.x), gy = f2bf(u.y),
                                         gz = f2bf(u.z), gw = f2bf(u.w);
                    *(ushort4*)&Ch[ar * 40 + kh + 4 * i] = make_ushort4(gx, gy, gz, gw);
                    *(ushort4*)&Cl[ar * 40 + kh + 4 * i] = make_ushort4(
                        f2bf(u.x - bf2f(gx)), f2bf(u.y - bf2f(gy)),
                        f2bf(u.z - bf2f(gz)), f2bf(u.w - bf2f(gw)));
                }
            }
            {
                const size_t bo = (size_t)(n0 + bc) * 384 + IN_DIM + k0 + kq;
                *(s8v*)&Bzh[bc * 40 + kq] = *(const s8v*)(WzThi + bo);
                *(s8v*)&Bzl[bc * 40 + kq] = *(const s8v*)(WzTlo + bo);
                *(s8v*)&Bhh[bc * 40 + kq] = *(const s8v*)(WhThi + bo);
                *(s8v*)&Bhl[bc * 40 + kq] = *(const s8v*)(WhTlo + bo);
            }
            __syncthreads();

            s8v av[4], aw[4], cv[4], cw[4];
#pragma unroll
            for (int mi = 0; mi < 4; mi++) {
                const int rr = (wmb + mi * 16 + lr) * 40 + lkb;
                av[mi] = *(const s8v*)&Ah[rr];
                aw[mi] = *(const s8v*)&Al[rr];
                cv[mi] = *(const s8v*)&Ch[rr];
                cw[mi] = *(const s8v*)&Cl[rr];
            }
#pragma unroll
            for (int ni = 0; ni < 2; ni++) {
                const int cc = (wnb + ni * 16 + lr) * 40 + lkb;
                const s8v bzv = *(const s8v*)&Bzh[cc];
                const s8v bzw = *(const s8v*)&Bzl[cc];
                const s8v bhv = *(const s8v*)&Bhh[cc];
                const s8v bhw = *(const s8v*)&Bhl[cc];
#pragma unroll
                for (int mi = 0; mi < 4; mi++) {
                    accz[mi][ni] = __builtin_amdgcn_mfma_f32_16x16x32_bf16(av[mi], bzv, accz[mi][ni], 0, 0, 0);
                    accz[mi][ni] = __builtin_amdgcn_mfma_f32_16x16x32_bf16(av[mi], bzw, accz[mi][ni], 0, 0, 0);
                    accz[mi][ni] = __builtin_amdgcn_mfma_f32_16x16x32_bf16(aw[mi], bzv, accz[mi][ni], 0, 0, 0);
                    acch[mi][ni] = __builtin_amdgcn_mfma_f32_16x16x32_bf16(cv[mi], bhv, acch[mi][ni], 0, 0, 0);
                    acch[mi][ni] = __builtin_amdgcn_mfma_f32_16x16x32_bf16(cv[mi], bhw, acch[mi][ni], 0, 0, 0);
                    acch[mi][ni] = __builtin_amdgcn_mfma_f32_16x16x32_bf16(cw[mi], bhv, acch[mi][ni], 0, 0, 0);
                }
            }
            __syncthreads();
        }
    }

    // ---- Epilogue ----
#pragma unroll
    for (int mi = 0; mi < 4; mi++) {
#pragma unroll
        for (int ni = 0; ni < 2; ni++) {
#pragma unroll
            for (int r = 0; r < 4; r++) {
                const int row = m0 + wmb + mi * 16 + drb + r;
                if (row >= M) continue;
                const int col = n0 + wnb + ni * 16 + lr;
                const float z = fsigmoid(accz[mi][ni][r] + b_z[col]);
                const float p = ftanh(acch[mi][ni][r] + b_h[col]);
                float o;
                if (STEP0) o = z * p;
                else       o = (1.f - z) * smh[(size_t)row * H + col] + z * p;
                if (grow0 + row == 0) o = 0.f;
                hout[(size_t)row * H + col] = o;
            }
        }
    }
}

// ---------------------------------------------------------------------------
// Edge gather (fp32, unchanged): per edge e of a chunk,
//   smh[e] = sum_n h[bg[e,n]];  smg[e] = sum_n sig(rx[e]+g[bg[e,n]]+b_ur)*h[..]
// ---------------------------------------------------------------------------
__global__ __launch_bounds__(256) void edge_kernel(
    const float* __restrict__ h, const float* __restrict__ g,
    const float* __restrict__ rx, const float* __restrict__ b_ur,
    const int* __restrict__ bgraph,
    float* __restrict__ smh, float* __restrict__ smg, int cc)
{
    const int e = blockIdx.x * 4 + (threadIdx.x >> 6);
    if (e >= cc) return;
    const int j = (threadIdx.x & 63) << 2;
    const float4 rv = *(const float4*)(rx + (size_t)e * H + j);
    const float4 bu = *(const float4*)(b_ur + j);
    float4 sh = make_float4(0.f, 0.f, 0.f, 0.f);
    float4 sg = make_float4(0.f, 0.f, 0.f, 0.f);
#pragma unroll
    for (int n = 0; n < NB; n++) {
        const int idx = bgraph[e * NB + n];
        const float4 hv = *(const float4*)(h + (size_t)idx * H + j);
        const float4 gv = *(const float4*)(g + (size_t)idx * H + j);
        sh.x += hv.x; sh.y += hv.y; sh.z += hv.z; sh.w += hv.w;
        float r;
        r = fsigmoid(rv.x + gv.x + bu.x); sg.x = fmaf(r, hv.x, sg.x);
        r = fsigmoid(rv.y + gv.y + bu.y); sg.y = fmaf(r, hv.y, sg.y);
        r = fsigmoid(rv.z + gv.z + bu.z); sg.z = fmaf(r, hv.z, sg.z);
        r = fsigmoid(rv.w + gv.w + bu.w); sg.w = fmaf(r, hv.w, sg.w);
    }
    *(float4*)(smh + (size_t)e * H + j) = sh;
    *(float4*)(smg + (size_t)e * H + j) = sg;
}

__global__ __launch_bounds__(256) void node_gather_kernel(
    const float* __restrict__ hmsg, const int* __restrict__ agraph,
    float* __restrict__ nei, int N)
{
    const int v = blockIdx.x * 4 + (threadIdx.x >> 6);
    if (v >= N) return;
    const int j = (threadIdx.x & 63) << 2;
    float4 s = make_float4(0.f, 0.f, 0.f, 0.f);
#pragma unroll
    for (int n = 0; n < NB; n++) {
        const int idx = agraph[v * NB + n];
        const float4 hv = *(const float4*)(hmsg + (size_t)idx * H + j);
        s.x += hv.x; s.y += hv.y; s.z += hv.z; s.w += hv.w;
    }
    *(float4*)(nei + (size_t)v * H + j) = s;
}

// ---------------------------------------------------------------------------
extern "C" void kernel_launch(void* const* d_in, const int* in_sizes, int n_in,
                              void* d_out, int out_size, void* d_ws, size_t ws_size,
                              hipStream_t stream)
{
    const float* fnode  = (const float*)d_in[0];
    const float* fmess  = (const float*)d_in[1];
    const int*   agraph = (const int*)  d_in[2];
    const int*   bgraph = (const int*)  d_in[3];
    const float* mask   = (const float*)d_in[4];
    const float* W_z    = (const float*)d_in[5];
    const float* b_z    = (const float*)d_in[6];
    const float* W_r    = (const float*)d_in[7];
    const float* U_r    = (const float*)d_in[8];
    const float* b_ur   = (const float*)d_in[9];
    const float* W_h    = (const float*)d_in[10];
    const float* b_h    = (const float*)d_in[11];
    const float* W_o    = (const float*)d_in[12];
    const float* b_o    = (const float*)d_in[13];

    const int N = in_sizes[0] / IN_DIM;   // 35000
    const int E = in_sizes[1] / IN_DIM;   // 80000
    const size_t EHf = (size_t)E * H;

    float* out_nodes = (float*)d_out;                   // [N,H]
    float* hA = (float*)d_out + (size_t)N * H;          // [E,H] final h

    // --- workspace: bf16 weight planes first, fp32 buffers after ---
    unsigned short* wb = (unsigned short*)d_ws;
    unsigned short* wz_hi = wb;
    unsigned short* wz_lo = wb + 98304;
    unsigned short* wh_hi = wb + 196608;
    unsigned short* wh_lo = wb + 294912;
    unsigned short* wr_hi = wb + 393216;
    unsigned short* wr_lo = wb + 425984;
    unsigned short* ur_hi = wb + 458752;
    unsigned short* ur_lo = wb + 524288;
    unsigned short* wo_hi = wb + 589824;
    unsigned short* wo_lo = wb + 688128;   // ends at 786432 ushorts
    float* wsf = (float*)d_ws + 393216;    // fp32 region
    const long avail = (long)(ws_size / 4) - 393216;

    const dim3 blk(256);
    #define GG(M) dim3(((M) + 127) / 128, 2)
    #define GU(M) dim3(((M) + 127) / 128, 4)

    // weight planes (once per launch; same work every call)
    wconv_kernel<<<384, blk, 0, stream>>>(W_z, wz_hi, wz_lo, 384);
    wconv_kernel<<<384, blk, 0, stream>>>(W_h, wh_hi, wh_lo, 384);
    wconv_kernel<<<128, blk, 0, stream>>>(W_r, wr_hi, wr_lo, 128);
    wconv_kernel<<<256, blk, 0, stream>>>(U_r, ur_hi, ur_lo, 256);
    wconv_kernel<<<384, blk, 0, stream>>>(W_o, wo_hi, wo_lo, 384);

    if (avail >= (long)(4 * EHf)) {
        // ---- Full tier: g, rx, smh, smg persistent ----
        float* g   = wsf;
        float* rx  = wsf + 1 * EHf;
        float* smh = wsf + 2 * EHf;
        float* smg = wsf + 3 * EHf;

        mfma_gemm_kernel<0><<<GG(E), blk, 0, stream>>>(
            fmess, IN_DIM, nullptr, 0, wr_hi, wr_lo, nullptr, nullptr, rx, E);
        mfma_update_kernel<true><<<GU(E), blk, 0, stream>>>(
            fmess, nullptr, nullptr, wz_hi, wz_lo, wh_hi, wh_lo, b_z, b_h, hA, E, 0);

        for (int t = 1; t < 5; t++) {
            mfma_gemm_kernel<0><<<GG(E), blk, 0, stream>>>(
                hA, H, nullptr, 0, ur_hi, ur_lo, nullptr, nullptr, g, E);
            edge_kernel<<<(E + 3) / 4, blk, 0, stream>>>(
                hA, g, rx, b_ur, bgraph, smh, smg, E);
            mfma_update_kernel<false><<<GU(E), blk, 0, stream>>>(
                fmess, smh, smg, wz_hi, wz_lo, wh_hi, wh_lo, b_z, b_h, hA, E, 0);
        }
        node_gather_kernel<<<(N + 3) / 4, blk, 0, stream>>>(hA, agraph, g, N);
        mfma_gemm_kernel<1><<<GG(N), blk, 0, stream>>>(
            fnode, IN_DIM, g, H, wo_hi, wo_lo, b_o, mask, out_nodes, N);

    } else if (avail >= (long)(3 * EHf + 128 * H)) {
        // ---- Tier 3: rx chunked ----
        float* g   = wsf;
        float* smh = wsf + 1 * EHf;
        float* smg = wsf + 2 * EHf;
        float* rxc = wsf + 3 * EHf;
        long CHr = (avail - 3 * (long)EHf) / H;
        if (CHr > E) CHr = E;
        CHr = (CHr / 128) * 128;

        mfma_update_kernel<true><<<GU(E), blk, 0, stream>>>(
            fmess, nullptr, nullptr, wz_hi, wz_lo, wh_hi, wh_lo, b_z, b_h, hA, E, 0);

        for (int t = 1; t < 5; t++) {
            mfma_gemm_kernel<0><<<GG(E), blk, 0, stream>>>(
                hA, H, nullptr, 0, ur_hi, ur_lo, nullptr, nullptr, g, E);
            for (int c0 = 0; c0 < E; c0 += (int)CHr) {
                const int cc = (E - c0 < (int)CHr) ? (E - c0) : (int)CHr;
                mfma_gemm_kernel<0><<<GG(cc), blk, 0, stream>>>(
                    fmess + (size_t)c0 * IN_DIM, IN_DIM, nullptr, 0,
                    wr_hi, wr_lo, nullptr, nullptr, rxc, cc);
                edge_kernel<<<(cc + 3) / 4, blk, 0, stream>>>(
                    hA, g, rxc, b_ur, bgraph + (size_t)c0 * NB,
                    smh + (size_t)c0 * H, smg + (size_t)c0 * H, cc);
            }
            mfma_update_kernel<false><<<GU(E), blk, 0, stream>>>(
                fmess, smh, smg, wz_hi, wz_lo, wh_hi, wh_lo, b_z, b_h, hA, E, 0);
        }
        node_gather_kernel<<<(N + 3) / 4, blk, 0, stream>>>(hA, agraph, g, N);
        mfma_gemm_kernel<1><<<GG(N), blk, 0, stream>>>(
            fnode, IN_DIM, g, H, wo_hi, wo_lo, b_o, mask, out_nodes, N);

    } else {
        // ---- Tier 4: minimal ws (wbuf + 2*EH); chunk bufs in out_nodes ----
        float* g  = wsf;
        float* hB = wsf + 1 * EHf;
        const int CH = 11136;                       // 3*CH*H <= N*H
        float* smh = out_nodes;
        float* smg = out_nodes + (size_t)CH * H;
        float* rxc = out_nodes + 2 * (size_t)CH * H;

        mfma_update_kernel<true><<<GU(E), blk, 0, stream>>>(
            fmess, nullptr, nullptr, wz_hi, wz_lo, wh_hi, wh_lo, b_z, b_h, hA, E, 0);

        float* hold = hA;
        float* hnew = hB;
        for (int t = 1; t < 5; t++) {
            mfma_gemm_kernel<0><<<GG(E), blk, 0, stream>>>(
                hold, H, nullptr, 0, ur_hi, ur_lo, nullptr, nullptr, g, E);
            for (int c0 = 0; c0 < E; c0 += CH) {
                const int cc = (E - c0 < CH) ? (E - c0) : CH;
                mfma_gemm_kernel<0><<<GG(cc), blk, 0, stream>>>(
                    fmess + (size_t)c0 * IN_DIM, IN_DIM, nullptr, 0,
                    wr_hi, wr_lo, nullptr, nullptr, rxc, cc);
                edge_kernel<<<(cc + 3) / 4, blk, 0, stream>>>(
                    hold, g, rxc, b_ur, bgraph + (size_t)c0 * NB, smh, smg, cc);
                mfma_update_kernel<false><<<GU(cc), blk, 0, stream>>>(
                    fmess + (size_t)c0 * IN_DIM, smh, smg,
                    wz_hi, wz_lo, wh_hi, wh_lo, b_z, b_h,
                    hnew + (size_t)c0 * H, cc, c0);
            }
            float* tmp = hold; hold = hnew; hnew = tmp;
        }
        // 4 swaps -> final h in hA
        node_gather_kernel<<<(N + 3) / 4, blk, 0, stream>>>(hA, agraph, g, N);
        mfma_gemm_kernel<1><<<GG(N), blk, 0, stream>>>(
            fnode, IN_DIM, g, H, wo_hi, wo_lo, b_o, mask, out_nodes, N);
    }
    #undef GG
    #undef GU
}

// Round 5
// 1605.195 us; speedup vs baseline: 2.4024x; 1.3834x over previous
//
#include <hip/hip_runtime.h>

#define H 256
#define NB 6
#define IN_DIM 128

typedef short s8v __attribute__((ext_vector_type(8)));
typedef float f4v __attribute__((ext_vector_type(4)));

__device__ __forceinline__ float fsigmoid(float x) {
    return 1.0f / (1.0f + __expf(-x));
}
__device__ __forceinline__ float ftanh(float x) {
    x = fminf(15.0f, fmaxf(-15.0f, x));
    float e = __expf(2.0f * x);
    return (e - 1.0f) / (e + 1.0f);
}
__device__ __forceinline__ unsigned short f2bf(float x) {
    unsigned u = __float_as_uint(x);
    u += 0x7fffu + ((u >> 16) & 1u);
    return (unsigned short)(u >> 16);
}
__device__ __forceinline__ float bf2f(unsigned short b) {
    return __uint_as_float(((unsigned)b) << 16);
}

// ---------------------------------------------------------------------------
// Weight convert+transpose: W [K][256] fp32 -> WT_hi/WT_lo [256][K] bf16.
// ---------------------------------------------------------------------------
__global__ __launch_bounds__(256) void wconv_kernel(
    const float* __restrict__ W, unsigned short* __restrict__ hi,
    unsigned short* __restrict__ lo, int K)
{
    const int i = blockIdx.x * 256 + threadIdx.x;   // i = n*K + k
    if (i >= K * 256) return;
    const int n = i / K, k = i - n * K;
    const float x = W[(size_t)k * H + n];
    const unsigned short h = f2bf(x);
    hi[i] = h;
    lo[i] = f2bf(x - bf2f(h));
}

// ---------------------------------------------------------------------------
// MFMA GEMM: C[M,256] = concat(A1[M,K1], A2[M,K2]) @ B[KT,256]
// A sources fp32 (f2bf on stage) or bf16 (copy stage) per template flag.
// B split hi/lo planes [256][KT]; 2 MFMAs per fragment (ah*bh + ah*bl).
// BM=128, BN=128, grid=(ceil(M/128), 2); 4 waves 2x2, wave tile 64x64.
// EPI: 0 plain; 1 relu(acc+bias)*mask[row].  OUTBF: store bf16 vs fp32.
// ---------------------------------------------------------------------------
template<int EPI, bool A1BF, bool A2BF, bool OUTBF>
__global__ __launch_bounds__(256, 2) void mfma_gemm_kernel(
    const void* __restrict__ A1, int K1, const void* __restrict__ A2, int K2,
    const unsigned short* __restrict__ BThi, const unsigned short* __restrict__ BTlo,
    const float* __restrict__ bias, const float* __restrict__ mask,
    void* __restrict__ C, int M)
{
    const int KT = K1 + K2;
    __shared__ __align__(16) unsigned short Ah[128 * 40];
    __shared__ __align__(16) unsigned short Bh[128 * 40];
    __shared__ __align__(16) unsigned short Bl[128 * 40];

    const int tid = threadIdx.x;
    const int m0 = blockIdx.x * 128, n0 = blockIdx.y * 128;
    const int lane = tid & 63;
    const int w = tid >> 6;
    const int wmb = (w >> 1) * 64, wnb = (w & 1) * 64;
    const int lr = lane & 15;
    const int lkb = (lane >> 4) * 8;
    const int drb = (lane >> 4) * 4;
    const int ar = tid >> 1, kh = (tid & 1) * 16;

    f4v acc[4][4];
#pragma unroll
    for (int mi = 0; mi < 4; mi++)
#pragma unroll
        for (int ni = 0; ni < 4; ni++) acc[mi][ni] = (f4v){0.f, 0.f, 0.f, 0.f};

    for (int k0 = 0; k0 < KT; k0 += 32) {
        const void* src; int lda, kk; bool srcbf;
        if (k0 < K1) { src = A1; lda = K1; kk = k0;      srcbf = A1BF; }
        else         { src = A2; lda = K2; kk = k0 - K1; srcbf = A2BF; }
        const int grow = m0 + ar;
        if (grow < M) {
            if (srcbf) {
                const unsigned short* p = (const unsigned short*)src + (size_t)grow * lda + kk + kh;
                *(s8v*)&Ah[ar * 40 + kh]     = *(const s8v*)p;
                *(s8v*)&Ah[ar * 40 + kh + 8] = *(const s8v*)(p + 8);
            } else {
                const float* p = (const float*)src + (size_t)grow * lda + kk + kh;
#pragma unroll
                for (int i = 0; i < 4; i++) {
                    const float4 v = *(const float4*)(p + 4 * i);
                    *(ushort4*)&Ah[ar * 40 + kh + 4 * i] =
                        make_ushort4(f2bf(v.x), f2bf(v.y), f2bf(v.z), f2bf(v.w));
                }
            }
        }
        {
            const size_t bo = (size_t)(n0 + ar) * KT + k0 + kh;
            *(s8v*)&Bh[ar * 40 + kh]     = *(const s8v*)(BThi + bo);
            *(s8v*)&Bh[ar * 40 + kh + 8] = *(const s8v*)(BThi + bo + 8);
            *(s8v*)&Bl[ar * 40 + kh]     = *(const s8v*)(BTlo + bo);
            *(s8v*)&Bl[ar * 40 + kh + 8] = *(const s8v*)(BTlo + bo + 8);
        }
        __syncthreads();

        s8v av[4];
#pragma unroll
        for (int mi = 0; mi < 4; mi++)
            av[mi] = *(const s8v*)&Ah[(wmb + mi * 16 + lr) * 40 + lkb];
#pragma unroll
        for (int ni = 0; ni < 4; ni++) {
            const int cc = (wnb + ni * 16 + lr) * 40 + lkb;
            const s8v bv = *(const s8v*)&Bh[cc];
            const s8v bw = *(const s8v*)&Bl[cc];
#pragma unroll
            for (int mi = 0; mi < 4; mi++) {
                acc[mi][ni] = __builtin_amdgcn_mfma_f32_16x16x32_bf16(av[mi], bv, acc[mi][ni], 0, 0, 0);
                acc[mi][ni] = __builtin_amdgcn_mfma_f32_16x16x32_bf16(av[mi], bw, acc[mi][ni], 0, 0, 0);
            }
        }
        __syncthreads();
    }

#pragma unroll
    for (int mi = 0; mi < 4; mi++) {
#pragma unroll
        for (int ni = 0; ni < 4; ni++) {
#pragma unroll
            for (int r = 0; r < 4; r++) {
                const int row = m0 + wmb + mi * 16 + drb + r;
                if (row >= M) continue;
                const int col = n0 + wnb + ni * 16 + lr;
                float v = acc[mi][ni][r];
                if (EPI == 1) v = fmaxf(v + bias[col], 0.f) * mask[row];
                if (OUTBF) ((unsigned short*)C)[(size_t)row * H + col] = f2bf(v);
                else       ((float*)C)[(size_t)row * H + col] = v;
            }
        }
    }
}

// ---------------------------------------------------------------------------
// GRU update, dual MFMA GEMM, fused X-term (K = 128 + 256):
//   accz = Xc@Wz[0:128] (+ smh@Wz[128:384] if !STEP0)
//   acch = Xc@Wh[0:128] (+ smg@Wh[128:384] if !STEP0)
//   z = sig(accz+b_z); p = tanh(acch+b_h)
//   h = STEP0 ? z*p : (1-z)*smh + z*p ; global row 0 -> 0
// smh/smg fp32 (epilogue-exact); A staged bf16-hi; B split, 2 MFMAs.
// BM=128, BN=64, grid=(ceil(M/128),4); wave tile 64x32.
// OUT32: fp32 store (final step) vs bf16 store (intermediate h).
// ---------------------------------------------------------------------------
template<bool STEP0, bool OUT32>
__global__ __launch_bounds__(256, 2) void mfma_update_kernel(
    const float* __restrict__ Xc,
    const float* __restrict__ smh, const float* __restrict__ smg,
    const unsigned short* __restrict__ WzThi, const unsigned short* __restrict__ WzTlo,
    const unsigned short* __restrict__ WhThi, const unsigned short* __restrict__ WhTlo,
    const float* __restrict__ b_z, const float* __restrict__ b_h,
    void* __restrict__ hout, int M, int grow0)
{
    __shared__ __align__(16) unsigned short Ah[128 * 40];
    __shared__ __align__(16) unsigned short Ch[128 * 40];
    __shared__ __align__(16) unsigned short Bzh[64 * 40];
    __shared__ __align__(16) unsigned short Bzl[64 * 40];
    __shared__ __align__(16) unsigned short Bhh[64 * 40];
    __shared__ __align__(16) unsigned short Bhl[64 * 40];

    const int tid = threadIdx.x;
    const int m0 = blockIdx.x * 128, n0 = blockIdx.y * 64;
    const int lane = tid & 63;
    const int w = tid >> 6;
    const int wmb = (w >> 1) * 64, wnb = (w & 1) * 32;
    const int lr = lane & 15;
    const int lkb = (lane >> 4) * 8;
    const int drb = (lane >> 4) * 4;
    const int ar = tid >> 1, kh = (tid & 1) * 16;   // A staging
    const int bc = tid >> 2, kq = (tid & 3) * 8;    // B staging

    f4v accz[4][2], acch[4][2];
#pragma unroll
    for (int mi = 0; mi < 4; mi++)
#pragma unroll
        for (int ni = 0; ni < 2; ni++) {
            accz[mi][ni] = (f4v){0.f, 0.f, 0.f, 0.f};
            acch[mi][ni] = (f4v){0.f, 0.f, 0.f, 0.f};
        }

    // ---- Phase X: K=0..127 over Xc (feeds both gates) ----
    for (int k0 = 0; k0 < IN_DIM; k0 += 32) {
        const int grow = m0 + ar;
        if (grow < M) {
            const float* p = Xc + (size_t)grow * IN_DIM + k0 + kh;
#pragma unroll
            for (int i = 0; i < 4; i++) {
                const float4 v = *(const float4*)(p + 4 * i);
                *(ushort4*)&Ah[ar * 40 + kh + 4 * i] =
                    make_ushort4(f2bf(v.x), f2bf(v.y), f2bf(v.z), f2bf(v.w));
            }
        }
        {
            const size_t bo = (size_t)(n0 + bc) * 384 + k0 + kq;
            *(s8v*)&Bzh[bc * 40 + kq] = *(const s8v*)(WzThi + bo);
            *(s8v*)&Bzl[bc * 40 + kq] = *(const s8v*)(WzTlo + bo);
            *(s8v*)&Bhh[bc * 40 + kq] = *(const s8v*)(WhThi + bo);
            *(s8v*)&Bhl[bc * 40 + kq] = *(const s8v*)(WhTlo + bo);
        }
        __syncthreads();

        s8v av[4];
#pragma unroll
        for (int mi = 0; mi < 4; mi++)
            av[mi] = *(const s8v*)&Ah[(wmb + mi * 16 + lr) * 40 + lkb];
#pragma unroll
        for (int ni = 0; ni < 2; ni++) {
            const int cc = (wnb + ni * 16 + lr) * 40 + lkb;
            const s8v bzv = *(const s8v*)&Bzh[cc];
            const s8v bzw = *(const s8v*)&Bzl[cc];
            const s8v bhv = *(const s8v*)&Bhh[cc];
            const s8v bhw = *(const s8v*)&Bhl[cc];
#pragma unroll
            for (int mi = 0; mi < 4; mi++) {
                accz[mi][ni] = __builtin_amdgcn_mfma_f32_16x16x32_bf16(av[mi], bzv, accz[mi][ni], 0, 0, 0);
                accz[mi][ni] = __builtin_amdgcn_mfma_f32_16x16x32_bf16(av[mi], bzw, accz[mi][ni], 0, 0, 0);
                acch[mi][ni] = __builtin_amdgcn_mfma_f32_16x16x32_bf16(av[mi], bhv, acch[mi][ni], 0, 0, 0);
                acch[mi][ni] = __builtin_amdgcn_mfma_f32_16x16x32_bf16(av[mi], bhw, acch[mi][ni], 0, 0, 0);
            }
        }
        __syncthreads();
    }

    // ---- Phase H: K=128..383; accz <- smh, acch <- smg ----
    if (!STEP0) {
        for (int k0 = 0; k0 < H; k0 += 32) {
            const int grow = m0 + ar;
            if (grow < M) {
                const float* p1 = smh + (size_t)grow * H + k0 + kh;
                const float* p2 = smg + (size_t)grow * H + k0 + kh;
#pragma unroll
                for (int i = 0; i < 4; i++) {
                    const float4 v = *(const float4*)(p1 + 4 * i);
                    *(ushort4*)&Ah[ar * 40 + kh + 4 * i] =
                        make_ushort4(f2bf(v.x), f2bf(v.y), f2bf(v.z), f2bf(v.w));
                    const float4 u = *(const float4*)(p2 + 4 * i);
                    *(ushort4*)&Ch[ar * 40 + kh + 4 * i] =
                        make_ushort4(f2bf(u.x), f2bf(u.y), f2bf(u.z), f2bf(u.w));
                }
            }
            {
                const size_t bo = (size_t)(n0 + bc) * 384 + IN_DIM + k0 + kq;
                *(s8v*)&Bzh[bc * 40 + kq] = *(const s8v*)(WzThi + bo);
                *(s8v*)&Bzl[bc * 40 + kq] = *(const s8v*)(WzTlo + bo);
                *(s8v*)&Bhh[bc * 40 + kq] = *(const s8v*)(WhThi + bo);
                *(s8v*)&Bhl[bc * 40 + kq] = *(const s8v*)(WhTlo + bo);
            }
            __syncthreads();

            s8v av[4], cv[4];
#pragma unroll
            for (int mi = 0; mi < 4; mi++) {
                const int rr = (wmb + mi * 16 + lr) * 40 + lkb;
                av[mi] = *(const s8v*)&Ah[rr];
                cv[mi] = *(const s8v*)&Ch[rr];
            }
#pragma unroll
            for (int ni = 0; ni < 2; ni++) {
                const int cc = (wnb + ni * 16 + lr) * 40 + lkb;
                const s8v bzv = *(const s8v*)&Bzh[cc];
                const s8v bzw = *(const s8v*)&Bzl[cc];
                const s8v bhv = *(const s8v*)&Bhh[cc];
                const s8v bhw = *(const s8v*)&Bhl[cc];
#pragma unroll
                for (int mi = 0; mi < 4; mi++) {
                    accz[mi][ni] = __builtin_amdgcn_mfma_f32_16x16x32_bf16(av[mi], bzv, accz[mi][ni], 0, 0, 0);
                    accz[mi][ni] = __builtin_amdgcn_mfma_f32_16x16x32_bf16(av[mi], bzw, accz[mi][ni], 0, 0, 0);
                    acch[mi][ni] = __builtin_amdgcn_mfma_f32_16x16x32_bf16(cv[mi], bhv, acch[mi][ni], 0, 0, 0);
                    acch[mi][ni] = __builtin_amdgcn_mfma_f32_16x16x32_bf16(cv[mi], bhw, acch[mi][ni], 0, 0, 0);
                }
            }
            __syncthreads();
        }
    }

    // ---- Epilogue ----
#pragma unroll
    for (int mi = 0; mi < 4; mi++) {
#pragma unroll
        for (int ni = 0; ni < 2; ni++) {
#pragma unroll
            for (int r = 0; r < 4; r++) {
                const int row = m0 + wmb + mi * 16 + drb + r;
                if (row >= M) continue;
                const int col = n0 + wnb + ni * 16 + lr;
                const float z = fsigmoid(accz[mi][ni][r] + b_z[col]);
                const float p = ftanh(acch[mi][ni][r] + b_h[col]);
                float o;
                if (STEP0) o = z * p;
                else       o = (1.f - z) * smh[(size_t)row * H + col] + z * p;
                if (grow0 + row == 0) o = 0.f;
                if (OUT32) ((float*)hout)[(size_t)row * H + col] = o;
                else       ((unsigned short*)hout)[(size_t)row * H + col] = f2bf(o);
            }
        }
    }
}

// ---------------------------------------------------------------------------
// Edge gather (bf16 h/g/rx in, fp32 sums out), chunk of cc edges:
//   smh[e] = sum_n h[bg[e,n]];  smg[e] = sum_n sig(rx[e]+g[bg[e,n]]+b_ur)*h[..]
// ---------------------------------------------------------------------------
__global__ __launch_bounds__(256) void edge_kernel(
    const unsigned short* __restrict__ h, const unsigned short* __restrict__ g,
    const unsigned short* __restrict__ rx, const float* __restrict__ b_ur,
    const int* __restrict__ bgraph,
    float* __restrict__ smh, float* __restrict__ smg, int cc)
{
    const int e = blockIdx.x * 4 + (threadIdx.x >> 6);
    if (e >= cc) return;
    const int j = (threadIdx.x & 63) << 2;
    const ushort4 rv4 = *(const ushort4*)(rx + (size_t)e * H + j);
    const float4 bu = *(const float4*)(b_ur + j);
    const float r0 = bf2f(rv4.x) + bu.x, r1 = bf2f(rv4.y) + bu.y;
    const float r2 = bf2f(rv4.z) + bu.z, r3 = bf2f(rv4.w) + bu.w;
    float4 sh = make_float4(0.f, 0.f, 0.f, 0.f);
    float4 sg = make_float4(0.f, 0.f, 0.f, 0.f);
#pragma unroll
    for (int n = 0; n < NB; n++) {
        const int idx = bgraph[e * NB + n];
        const ushort4 hv4 = *(const ushort4*)(h + (size_t)idx * H + j);
        const ushort4 gv4 = *(const ushort4*)(g + (size_t)idx * H + j);
        const float h0 = bf2f(hv4.x), h1 = bf2f(hv4.y), h2 = bf2f(hv4.z), h3 = bf2f(hv4.w);
        sh.x += h0; sh.y += h1; sh.z += h2; sh.w += h3;
        sg.x = fmaf(fsigmoid(r0 + bf2f(gv4.x)), h0, sg.x);
        sg.y = fmaf(fsigmoid(r1 + bf2f(gv4.y)), h1, sg.y);
        sg.z = fmaf(fsigmoid(r2 + bf2f(gv4.z)), h2, sg.z);
        sg.w = fmaf(fsigmoid(r3 + bf2f(gv4.w)), h3, sg.w);
    }
    *(float4*)(smh + (size_t)e * H + j) = sh;
    *(float4*)(smg + (size_t)e * H + j) = sg;
}

// ---------------------------------------------------------------------------
// Node gather: nei_bf16[v] = sum_n h_fp32[agraph[v,n]]
// ---------------------------------------------------------------------------
__global__ __launch_bounds__(256) void node_gather_kernel(
    const float* __restrict__ hmsg, const int* __restrict__ agraph,
    unsigned short* __restrict__ nei, int N)
{
    const int v = blockIdx.x * 4 + (threadIdx.x >> 6);
    if (v >= N) return;
    const int j = (threadIdx.x & 63) << 2;
    float4 s = make_float4(0.f, 0.f, 0.f, 0.f);
#pragma unroll
    for (int n = 0; n < NB; n++) {
        const int idx = agraph[v * NB + n];
        const float4 hv = *(const float4*)(hmsg + (size_t)idx * H + j);
        s.x += hv.x; s.y += hv.y; s.z += hv.z; s.w += hv.w;
    }
    *(ushort4*)(nei + (size_t)v * H + j) =
        make_ushort4(f2bf(s.x), f2bf(s.y), f2bf(s.z), f2bf(s.w));
}

// ---------------------------------------------------------------------------
extern "C" void kernel_launch(void* const* d_in, const int* in_sizes, int n_in,
                              void* d_out, int out_size, void* d_ws, size_t ws_size,
                              hipStream_t stream)
{
    const float* fnode  = (const float*)d_in[0];
    const float* fmess  = (const float*)d_in[1];
    const int*   agraph = (const int*)  d_in[2];
    const int*   bgraph = (const int*)  d_in[3];
    const float* mask   = (const float*)d_in[4];
    const float* W_z    = (const float*)d_in[5];
    const float* b_z    = (const float*)d_in[6];
    const float* W_r    = (const float*)d_in[7];
    const float* U_r    = (const float*)d_in[8];
    const float* b_ur   = (const float*)d_in[9];
    const float* W_h    = (const float*)d_in[10];
    const float* b_h    = (const float*)d_in[11];
    const float* W_o    = (const float*)d_in[12];
    const float* b_o    = (const float*)d_in[13];

    const int N = in_sizes[0] / IN_DIM;   // 35000
    const int E = in_sizes[1] / IN_DIM;   // 80000
    const size_t EHu = (size_t)E * H;     // elements per [E,H] plane

    float* out_nodes = (float*)d_out;                    // [N,H] fp32
    float* hA        = (float*)d_out + (size_t)N * H;    // [E,H] fp32 final h
    // intermediate bf16 h ping-pong lives inside the hA region (2 x 41 MB)
    unsigned short* hb0 = (unsigned short*)hA;
    unsigned short* hb1 = hb0 + EHu;

    // --- workspace layout: bf16 weight planes | rx | g | smh | smg ---
    unsigned short* wb = (unsigned short*)d_ws;
    unsigned short* wz_hi = wb;
    unsigned short* wz_lo = wb + 98304;
    unsigned short* wh_hi = wb + 196608;
    unsigned short* wh_lo = wb + 294912;
    unsigned short* wr_hi = wb + 393216;
    unsigned short* wr_lo = wb + 425984;
    unsigned short* ur_hi = wb + 458752;
    unsigned short* ur_lo = wb + 524288;
    unsigned short* wo_hi = wb + 589824;
    unsigned short* wo_lo = wb + 688128;   // ends at 786432 ushorts
    unsigned short* rxb = wb + 786432;
    unsigned short* gb  = rxb + EHu;

    const size_t used_b = 786432ull * 2 + 2 * EHu * 2;   // planes + rx + g
    float* fpool = (float*)((char*)d_ws + used_b);
    const size_t left_f = (ws_size - used_b) / 4;
    const int CH = (2 * EHu <= left_f) ? E : (E + 1) / 2;   // chunk rows
    float* smh = fpool;
    float* smg = fpool + (size_t)CH * H;

    const dim3 blk(256);
    #define GG(M) dim3(((M) + 127) / 128, 2)
    #define GU(M) dim3(((M) + 127) / 128, 4)

    // weight planes (identical work every call)
    wconv_kernel<<<384, blk, 0, stream>>>(W_z, wz_hi, wz_lo, 384);
    wconv_kernel<<<384, blk, 0, stream>>>(W_h, wh_hi, wh_lo, 384);
    wconv_kernel<<<128, blk, 0, stream>>>(W_r, wr_hi, wr_lo, 128);
    wconv_kernel<<<256, blk, 0, stream>>>(U_r, ur_hi, ur_lo, 256);
    wconv_kernel<<<384, blk, 0, stream>>>(W_o, wo_hi, wo_lo, 384);

    // rx = fmess @ W_r  (bf16 out)
    mfma_gemm_kernel<0, false, false, true><<<GG(E), blk, 0, stream>>>(
        fmess, IN_DIM, nullptr, 0, wr_hi, wr_lo, nullptr, nullptr, rxb, E);
    // step 0: h1 = sig(zx)*tanh(hx)  (bf16 out -> hb0)
    mfma_update_kernel<true, false><<<GU(E), blk, 0, stream>>>(
        fmess, nullptr, nullptr, wz_hi, wz_lo, wh_hi, wh_lo, b_z, b_h, hb0, E, 0);

    unsigned short* hcur = hb0;
    unsigned short* hnxt = hb1;
    for (int t = 1; t < 5; t++) {
        // g = h @ U_r  (bf16 in/out, full E)
        mfma_gemm_kernel<0, true, false, true><<<GG(E), blk, 0, stream>>>(
            hcur, H, nullptr, 0, ur_hi, ur_lo, nullptr, nullptr, gb, E);
        for (int c0 = 0; c0 < E; c0 += CH) {
            const int cc = (E - c0 < CH) ? (E - c0) : CH;
            edge_kernel<<<(cc + 3) / 4, blk, 0, stream>>>(
                hcur, gb, rxb + (size_t)c0 * H, b_ur, bgraph + (size_t)c0 * NB,
                smh, smg, cc);
            if (t < 4)
                mfma_update_kernel<false, false><<<GU(cc), blk, 0, stream>>>(
                    fmess + (size_t)c0 * IN_DIM, smh, smg,
                    wz_hi, wz_lo, wh_hi, wh_lo, b_z, b_h,
                    hnxt + (size_t)c0 * H, cc, c0);
            else
                mfma_update_kernel<false, true><<<GU(cc), blk, 0, stream>>>(
                    fmess + (size_t)c0 * IN_DIM, smh, smg,
                    wz_hi, wz_lo, wh_hi, wh_lo, b_z, b_h,
                    hA + (size_t)c0 * H, cc, c0);
        }
        unsigned short* tmp = hcur; hcur = hnxt; hnxt = tmp;
    }
    // hcur parity: t=3 wrote hb1, so t=4's fp32 writes over hb0 first -- safe.

    // readout: nei (bf16, reuse gb) then node GEMM
    node_gather_kernel<<<(N + 3) / 4, blk, 0, stream>>>(hA, agraph, gb, N);
    mfma_gemm_kernel<1, false, true, false><<<GG(N), blk, 0, stream>>>(
        fnode, IN_DIM, gb, H, wo_hi, wo_lo, b_o, mask, out_nodes, N);
    #undef GG
    #undef GU
}

// Round 6
// 1359.294 us; speedup vs baseline: 2.8370x; 1.1809x over previous
//
#include <hip/hip_runtime.h>

#define H 256
#define NB 6
#define IN_DIM 128

typedef short s8v __attribute__((ext_vector_type(8)));
typedef float f4v __attribute__((ext_vector_type(4)));

__device__ __forceinline__ float fsigmoid(float x) {
    return 1.0f / (1.0f + __expf(-x));
}
__device__ __forceinline__ float ftanh(float x) {
    x = fminf(15.0f, fmaxf(-15.0f, x));
    float e = __expf(2.0f * x);
    return (e - 1.0f) / (e + 1.0f);
}
__device__ __forceinline__ unsigned short f2bf(float x) {
    unsigned u = __float_as_uint(x);
    u += 0x7fffu + ((u >> 16) & 1u);
    return (unsigned short)(u >> 16);
}
__device__ __forceinline__ float bf2f(unsigned short b) {
    return __uint_as_float(((unsigned)b) << 16);
}

// ---------------------------------------------------------------------------
// Weight convert+transpose: W [K][256] fp32 -> WT_hi/WT_lo [256][K] bf16.
// (Pass W pre-offset by 128*H to grab row-slices 128..)
// ---------------------------------------------------------------------------
__global__ __launch_bounds__(256) void wconv_kernel(
    const float* __restrict__ W, unsigned short* __restrict__ hi,
    unsigned short* __restrict__ lo, int K)
{
    const int i = blockIdx.x * 256 + threadIdx.x;   // i = n*K + k
    if (i >= K * 256) return;
    const int n = i / K, k = i - n * K;
    const float x = W[(size_t)k * H + n];
    const unsigned short h = f2bf(x);
    hi[i] = h;
    lo[i] = f2bf(x - bf2f(h));
}

// ---------------------------------------------------------------------------
// Triple-gate precompute: for all msgs,
//   rxb = fmess@W_r + b_ur; zxb = fmess@Wz[0:128] + b_z; hxb = fmess@Wh[0:128] + b_h
// all stored bf16 [M,256]. B planes [256][128]. BM=128, BN=64, grid (M/128, 4).
// ---------------------------------------------------------------------------
__global__ __launch_bounds__(256, 2) void precompute3_kernel(
    const float* __restrict__ X,
    const unsigned short* __restrict__ WrH, const unsigned short* __restrict__ WrL,
    const unsigned short* __restrict__ WzH, const unsigned short* __restrict__ WzL,
    const unsigned short* __restrict__ WhH, const unsigned short* __restrict__ WhL,
    const float* __restrict__ b_ur, const float* __restrict__ b_z,
    const float* __restrict__ b_h,
    unsigned short* __restrict__ rxb, unsigned short* __restrict__ zxb,
    unsigned short* __restrict__ hxb, int M)
{
    __shared__ __align__(16) unsigned short Ah[128 * 40];
    __shared__ __align__(16) unsigned short Brh[64 * 40];
    __shared__ __align__(16) unsigned short Brl[64 * 40];
    __shared__ __align__(16) unsigned short Bzh[64 * 40];
    __shared__ __align__(16) unsigned short Bzl[64 * 40];
    __shared__ __align__(16) unsigned short Bhh[64 * 40];
    __shared__ __align__(16) unsigned short Bhl[64 * 40];

    const int tid = threadIdx.x;
    const int m0 = blockIdx.x * 128, n0 = blockIdx.y * 64;
    const int lane = tid & 63;
    const int w = tid >> 6;
    const int wmb = (w >> 1) * 64, wnb = (w & 1) * 32;
    const int lr = lane & 15;
    const int lkb = (lane >> 4) * 8;
    const int drb = (lane >> 4) * 4;
    const int ar = tid >> 1, kh = (tid & 1) * 16;
    const int bc = tid >> 2, kq = (tid & 3) * 8;

    f4v ar_[4][2], az_[4][2], ah_[4][2];
#pragma unroll
    for (int mi = 0; mi < 4; mi++)
#pragma unroll
        for (int ni = 0; ni < 2; ni++) {
            ar_[mi][ni] = (f4v){0.f, 0.f, 0.f, 0.f};
            az_[mi][ni] = (f4v){0.f, 0.f, 0.f, 0.f};
            ah_[mi][ni] = (f4v){0.f, 0.f, 0.f, 0.f};
        }

    for (int k0 = 0; k0 < IN_DIM; k0 += 32) {
        const int grow = m0 + ar;
        if (grow < M) {
            const float* p = X + (size_t)grow * IN_DIM + k0 + kh;
#pragma unroll
            for (int i = 0; i < 4; i++) {
                const float4 v = *(const float4*)(p + 4 * i);
                *(ushort4*)&Ah[ar * 40 + kh + 4 * i] =
                    make_ushort4(f2bf(v.x), f2bf(v.y), f2bf(v.z), f2bf(v.w));
            }
        }
        {
            const size_t bo = (size_t)(n0 + bc) * IN_DIM + k0 + kq;
            *(s8v*)&Brh[bc * 40 + kq] = *(const s8v*)(WrH + bo);
            *(s8v*)&Brl[bc * 40 + kq] = *(const s8v*)(WrL + bo);
            *(s8v*)&Bzh[bc * 40 + kq] = *(const s8v*)(WzH + bo);
            *(s8v*)&Bzl[bc * 40 + kq] = *(const s8v*)(WzL + bo);
            *(s8v*)&Bhh[bc * 40 + kq] = *(const s8v*)(WhH + bo);
            *(s8v*)&Bhl[bc * 40 + kq] = *(const s8v*)(WhL + bo);
        }
        __syncthreads();

        s8v av[4];
#pragma unroll
        for (int mi = 0; mi < 4; mi++)
            av[mi] = *(const s8v*)&Ah[(wmb + mi * 16 + lr) * 40 + lkb];
#pragma unroll
        for (int ni = 0; ni < 2; ni++) {
            const int cc = (wnb + ni * 16 + lr) * 40 + lkb;
            const s8v rv = *(const s8v*)&Brh[cc];
            const s8v rw = *(const s8v*)&Brl[cc];
            const s8v zv = *(const s8v*)&Bzh[cc];
            const s8v zw = *(const s8v*)&Bzl[cc];
            const s8v hv = *(const s8v*)&Bhh[cc];
            const s8v hw = *(const s8v*)&Bhl[cc];
#pragma unroll
            for (int mi = 0; mi < 4; mi++) {
                ar_[mi][ni] = __builtin_amdgcn_mfma_f32_16x16x32_bf16(av[mi], rv, ar_[mi][ni], 0, 0, 0);
                ar_[mi][ni] = __builtin_amdgcn_mfma_f32_16x16x32_bf16(av[mi], rw, ar_[mi][ni], 0, 0, 0);
                az_[mi][ni] = __builtin_amdgcn_mfma_f32_16x16x32_bf16(av[mi], zv, az_[mi][ni], 0, 0, 0);
                az_[mi][ni] = __builtin_amdgcn_mfma_f32_16x16x32_bf16(av[mi], zw, az_[mi][ni], 0, 0, 0);
                ah_[mi][ni] = __builtin_amdgcn_mfma_f32_16x16x32_bf16(av[mi], hv, ah_[mi][ni], 0, 0, 0);
                ah_[mi][ni] = __builtin_amdgcn_mfma_f32_16x16x32_bf16(av[mi], hw, ah_[mi][ni], 0, 0, 0);
            }
        }
        __syncthreads();
    }

#pragma unroll
    for (int mi = 0; mi < 4; mi++) {
#pragma unroll
        for (int ni = 0; ni < 2; ni++) {
#pragma unroll
            for (int r = 0; r < 4; r++) {
                const int row = m0 + wmb + mi * 16 + drb + r;
                if (row >= M) continue;
                const int col = n0 + wnb + ni * 16 + lr;
                const size_t off = (size_t)row * H + col;
                rxb[off] = f2bf(ar_[mi][ni][r] + b_ur[col]);
                zxb[off] = f2bf(az_[mi][ni][r] + b_z[col]);
                hxb[off] = f2bf(ah_[mi][ni][r] + b_h[col]);
            }
        }
    }
}

// ---------------------------------------------------------------------------
// Step 0 elementwise: h = sig(zx)*tanh(hx) (bf16 in/out); row 0 -> 0.
// ---------------------------------------------------------------------------
__global__ __launch_bounds__(256) void step0_kernel(
    const unsigned short* __restrict__ zxb, const unsigned short* __restrict__ hxb,
    unsigned short* __restrict__ h, long total4)
{
    const long i = (long)blockIdx.x * 256 + threadIdx.x;
    if (i >= total4) return;
    const ushort4 z4 = ((const ushort4*)zxb)[i];
    const ushort4 h4 = ((const ushort4*)hxb)[i];
    ushort4 o;
    o.x = f2bf(fsigmoid(bf2f(z4.x)) * ftanh(bf2f(h4.x)));
    o.y = f2bf(fsigmoid(bf2f(z4.y)) * ftanh(bf2f(h4.y)));
    o.z = f2bf(fsigmoid(bf2f(z4.z)) * ftanh(bf2f(h4.z)));
    o.w = f2bf(fsigmoid(bf2f(z4.w)) * ftanh(bf2f(h4.w)));
    if (i < H / 4) o = make_ushort4(0, 0, 0, 0);
    ((ushort4*)h)[i] = o;
}

// ---------------------------------------------------------------------------
// MFMA GEMM (round-5 proven): C = concat(A1,A2) @ B, B split hi/lo [256][KT].
// ---------------------------------------------------------------------------
template<int EPI, bool A1BF, bool A2BF, bool OUTBF>
__global__ __launch_bounds__(256, 2) void mfma_gemm_kernel(
    const void* __restrict__ A1, int K1, const void* __restrict__ A2, int K2,
    const unsigned short* __restrict__ BThi, const unsigned short* __restrict__ BTlo,
    const float* __restrict__ bias, const float* __restrict__ mask,
    void* __restrict__ C, int M)
{
    const int KT = K1 + K2;
    __shared__ __align__(16) unsigned short Ah[128 * 40];
    __shared__ __align__(16) unsigned short Bh[128 * 40];
    __shared__ __align__(16) unsigned short Bl[128 * 40];

    const int tid = threadIdx.x;
    const int m0 = blockIdx.x * 128, n0 = blockIdx.y * 128;
    const int lane = tid & 63;
    const int w = tid >> 6;
    const int wmb = (w >> 1) * 64, wnb = (w & 1) * 64;
    const int lr = lane & 15;
    const int lkb = (lane >> 4) * 8;
    const int drb = (lane >> 4) * 4;
    const int ar = tid >> 1, kh = (tid & 1) * 16;

    f4v acc[4][4];
#pragma unroll
    for (int mi = 0; mi < 4; mi++)
#pragma unroll
        for (int ni = 0; ni < 4; ni++) acc[mi][ni] = (f4v){0.f, 0.f, 0.f, 0.f};

    for (int k0 = 0; k0 < KT; k0 += 32) {
        const void* src; int lda, kk; bool srcbf;
        if (k0 < K1) { src = A1; lda = K1; kk = k0;      srcbf = A1BF; }
        else         { src = A2; lda = K2; kk = k0 - K1; srcbf = A2BF; }
        const int grow = m0 + ar;
        if (grow < M) {
            if (srcbf) {
                const unsigned short* p = (const unsigned short*)src + (size_t)grow * lda + kk + kh;
                *(s8v*)&Ah[ar * 40 + kh]     = *(const s8v*)p;
                *(s8v*)&Ah[ar * 40 + kh + 8] = *(const s8v*)(p + 8);
            } else {
                const float* p = (const float*)src + (size_t)grow * lda + kk + kh;
#pragma unroll
                for (int i = 0; i < 4; i++) {
                    const float4 v = *(const float4*)(p + 4 * i);
                    *(ushort4*)&Ah[ar * 40 + kh + 4 * i] =
                        make_ushort4(f2bf(v.x), f2bf(v.y), f2bf(v.z), f2bf(v.w));
                }
            }
        }
        {
            const size_t bo = (size_t)(n0 + ar) * KT + k0 + kh;
            *(s8v*)&Bh[ar * 40 + kh]     = *(const s8v*)(BThi + bo);
            *(s8v*)&Bh[ar * 40 + kh + 8] = *(const s8v*)(BThi + bo + 8);
            *(s8v*)&Bl[ar * 40 + kh]     = *(const s8v*)(BTlo + bo);
            *(s8v*)&Bl[ar * 40 + kh + 8] = *(const s8v*)(BTlo + bo + 8);
        }
        __syncthreads();

        s8v av[4];
#pragma unroll
        for (int mi = 0; mi < 4; mi++)
            av[mi] = *(const s8v*)&Ah[(wmb + mi * 16 + lr) * 40 + lkb];
#pragma unroll
        for (int ni = 0; ni < 4; ni++) {
            const int cc = (wnb + ni * 16 + lr) * 40 + lkb;
            const s8v bv = *(const s8v*)&Bh[cc];
            const s8v bw = *(const s8v*)&Bl[cc];
#pragma unroll
            for (int mi = 0; mi < 4; mi++) {
                acc[mi][ni] = __builtin_amdgcn_mfma_f32_16x16x32_bf16(av[mi], bv, acc[mi][ni], 0, 0, 0);
                acc[mi][ni] = __builtin_amdgcn_mfma_f32_16x16x32_bf16(av[mi], bw, acc[mi][ni], 0, 0, 0);
            }
        }
        __syncthreads();
    }

#pragma unroll
    for (int mi = 0; mi < 4; mi++) {
#pragma unroll
        for (int ni = 0; ni < 4; ni++) {
#pragma unroll
            for (int r = 0; r < 4; r++) {
                const int row = m0 + wmb + mi * 16 + drb + r;
                if (row >= M) continue;
                const int col = n0 + wnb + ni * 16 + lr;
                float v = acc[mi][ni][r];
                if (EPI == 1) v = fmaxf(v + bias[col], 0.f) * mask[row];
                if (OUTBF) ((unsigned short*)C)[(size_t)row * H + col] = f2bf(v);
                else       ((float*)C)[(size_t)row * H + col] = v;
            }
        }
    }
}

// ---------------------------------------------------------------------------
// GRU update, K=256 only (X-phase hoisted):
//   accz = smh@Wz[128:384]; acch = smg@Wh[128:384]
//   z = sig(accz + zx); p = tanh(acch + hx)
//   h = (1-z)*smh + z*p ; global row 0 -> 0
// smh/smg/zx/hx all bf16. BM=128, BN=64, grid (M/128, 4).
// ---------------------------------------------------------------------------
template<bool OUT32>
__global__ __launch_bounds__(256, 2) void mfma_update2_kernel(
    const unsigned short* __restrict__ smh, const unsigned short* __restrict__ smg,
    const unsigned short* __restrict__ WzH, const unsigned short* __restrict__ WzL,
    const unsigned short* __restrict__ WhH, const unsigned short* __restrict__ WhL,
    const unsigned short* __restrict__ zxb, const unsigned short* __restrict__ hxb,
    void* __restrict__ hout, int M, int grow0)
{
    __shared__ __align__(16) unsigned short Ah[128 * 40];
    __shared__ __align__(16) unsigned short Ch[128 * 40];
    __shared__ __align__(16) unsigned short Bzh[64 * 40];
    __shared__ __align__(16) unsigned short Bzl[64 * 40];
    __shared__ __align__(16) unsigned short Bhh[64 * 40];
    __shared__ __align__(16) unsigned short Bhl[64 * 40];

    const int tid = threadIdx.x;
    const int m0 = blockIdx.x * 128, n0 = blockIdx.y * 64;
    const int lane = tid & 63;
    const int w = tid >> 6;
    const int wmb = (w >> 1) * 64, wnb = (w & 1) * 32;
    const int lr = lane & 15;
    const int lkb = (lane >> 4) * 8;
    const int drb = (lane >> 4) * 4;
    const int ar = tid >> 1, kh = (tid & 1) * 16;
    const int bc = tid >> 2, kq = (tid & 3) * 8;

    f4v accz[4][2], acch[4][2];
#pragma unroll
    for (int mi = 0; mi < 4; mi++)
#pragma unroll
        for (int ni = 0; ni < 2; ni++) {
            accz[mi][ni] = (f4v){0.f, 0.f, 0.f, 0.f};
            acch[mi][ni] = (f4v){0.f, 0.f, 0.f, 0.f};
        }

    for (int k0 = 0; k0 < H; k0 += 32) {
        const int grow = m0 + ar;
        if (grow < M) {
            const unsigned short* p1 = smh + (size_t)grow * H + k0 + kh;
            const unsigned short* p2 = smg + (size_t)grow * H + k0 + kh;
            *(s8v*)&Ah[ar * 40 + kh]     = *(const s8v*)p1;
            *(s8v*)&Ah[ar * 40 + kh + 8] = *(const s8v*)(p1 + 8);
            *(s8v*)&Ch[ar * 40 + kh]     = *(const s8v*)p2;
            *(s8v*)&Ch[ar * 40 + kh + 8] = *(const s8v*)(p2 + 8);
        }
        {
            const size_t bo = (size_t)(n0 + bc) * H + k0 + kq;
            *(s8v*)&Bzh[bc * 40 + kq] = *(const s8v*)(WzH + bo);
            *(s8v*)&Bzl[bc * 40 + kq] = *(const s8v*)(WzL + bo);
            *(s8v*)&Bhh[bc * 40 + kq] = *(const s8v*)(WhH + bo);
            *(s8v*)&Bhl[bc * 40 + kq] = *(const s8v*)(WhL + bo);
        }
        __syncthreads();

        s8v av[4], cv[4];
#pragma unroll
        for (int mi = 0; mi < 4; mi++) {
            const int rr = (wmb + mi * 16 + lr) * 40 + lkb;
            av[mi] = *(const s8v*)&Ah[rr];
            cv[mi] = *(const s8v*)&Ch[rr];
        }
#pragma unroll
        for (int ni = 0; ni < 2; ni++) {
            const int cc = (wnb + ni * 16 + lr) * 40 + lkb;
            const s8v bzv = *(const s8v*)&Bzh[cc];
            const s8v bzw = *(const s8v*)&Bzl[cc];
            const s8v bhv = *(const s8v*)&Bhh[cc];
            const s8v bhw = *(const s8v*)&Bhl[cc];
#pragma unroll
            for (int mi = 0; mi < 4; mi++) {
                accz[mi][ni] = __builtin_amdgcn_mfma_f32_16x16x32_bf16(av[mi], bzv, accz[mi][ni], 0, 0, 0);
                accz[mi][ni] = __builtin_amdgcn_mfma_f32_16x16x32_bf16(av[mi], bzw, accz[mi][ni], 0, 0, 0);
                acch[mi][ni] = __builtin_amdgcn_mfma_f32_16x16x32_bf16(cv[mi], bhv, acch[mi][ni], 0, 0, 0);
                acch[mi][ni] = __builtin_amdgcn_mfma_f32_16x16x32_bf16(cv[mi], bhw, acch[mi][ni], 0, 0, 0);
            }
        }
        __syncthreads();
    }

#pragma unroll
    for (int mi = 0; mi < 4; mi++) {
#pragma unroll
        for (int ni = 0; ni < 2; ni++) {
#pragma unroll
            for (int r = 0; r < 4; r++) {
                const int row = m0 + wmb + mi * 16 + drb + r;
                if (row >= M) continue;
                const int col = n0 + wnb + ni * 16 + lr;
                const size_t off = (size_t)row * H + col;
                const float z = fsigmoid(accz[mi][ni][r] + bf2f(zxb[off]));
                const float p = ftanh(acch[mi][ni][r] + bf2f(hxb[off]));
                float o = (1.f - z) * bf2f(smh[off]) + z * p;
                if (grow0 + row == 0) o = 0.f;
                if (OUT32) ((float*)hout)[off] = o;
                else       ((unsigned short*)hout)[off] = f2bf(o);
            }
        }
    }
}

// ---------------------------------------------------------------------------
// Edge gather: smh[e]=sum h[bg[e,n]]; smg[e]=sum sig(rx'[e]+g[..])*h[..]
// (rx' has b_ur pre-folded). bf16 in, bf16 out (fp32 accumulation inside).
// ---------------------------------------------------------------------------
__global__ __launch_bounds__(256) void edge_kernel(
    const unsigned short* __restrict__ h, const unsigned short* __restrict__ g,
    const unsigned short* __restrict__ rx, const int* __restrict__ bgraph,
    unsigned short* __restrict__ smh, unsigned short* __restrict__ smg, int cc)
{
    const int e = blockIdx.x * 4 + (threadIdx.x >> 6);
    if (e >= cc) return;
    const int j = (threadIdx.x & 63) << 2;
    const ushort4 rv4 = *(const ushort4*)(rx + (size_t)e * H + j);
    const float r0 = bf2f(rv4.x), r1 = bf2f(rv4.y), r2 = bf2f(rv4.z), r3 = bf2f(rv4.w);
    float4 sh = make_float4(0.f, 0.f, 0.f, 0.f);
    float4 sg = make_float4(0.f, 0.f, 0.f, 0.f);
#pragma unroll
    for (int n = 0; n < NB; n++) {
        const int idx = bgraph[e * NB + n];
        const ushort4 hv4 = *(const ushort4*)(h + (size_t)idx * H + j);
        const ushort4 gv4 = *(const ushort4*)(g + (size_t)idx * H + j);
        const float h0 = bf2f(hv4.x), h1 = bf2f(hv4.y), h2 = bf2f(hv4.z), h3 = bf2f(hv4.w);
        sh.x += h0; sh.y += h1; sh.z += h2; sh.w += h3;
        sg.x = fmaf(fsigmoid(r0 + bf2f(gv4.x)), h0, sg.x);
        sg.y = fmaf(fsigmoid(r1 + bf2f(gv4.y)), h1, sg.y);
        sg.z = fmaf(fsigmoid(r2 + bf2f(gv4.z)), h2, sg.z);
        sg.w = fmaf(fsigmoid(r3 + bf2f(gv4.w)), h3, sg.w);
    }
    *(ushort4*)(smh + (size_t)e * H + j) =
        make_ushort4(f2bf(sh.x), f2bf(sh.y), f2bf(sh.z), f2bf(sh.w));
    *(ushort4*)(smg + (size_t)e * H + j) =
        make_ushort4(f2bf(sg.x), f2bf(sg.y), f2bf(sg.z), f2bf(sg.w));
}

// ---------------------------------------------------------------------------
// Node gather: nei_bf16[v] = sum_n h_fp32[agraph[v,n]]
// ---------------------------------------------------------------------------
__global__ __launch_bounds__(256) void node_gather_kernel(
    const float* __restrict__ hmsg, const int* __restrict__ agraph,
    unsigned short* __restrict__ nei, int N)
{
    const int v = blockIdx.x * 4 + (threadIdx.x >> 6);
    if (v >= N) return;
    const int j = (threadIdx.x & 63) << 2;
    float4 s = make_float4(0.f, 0.f, 0.f, 0.f);
#pragma unroll
    for (int n = 0; n < NB; n++) {
        const int idx = agraph[v * NB + n];
        const float4 hv = *(const float4*)(hmsg + (size_t)idx * H + j);
        s.x += hv.x; s.y += hv.y; s.z += hv.z; s.w += hv.w;
    }
    *(ushort4*)(nei + (size_t)v * H + j) =
        make_ushort4(f2bf(s.x), f2bf(s.y), f2bf(s.z), f2bf(s.w));
}

// ---------------------------------------------------------------------------
extern "C" void kernel_launch(void* const* d_in, const int* in_sizes, int n_in,
                              void* d_out, int out_size, void* d_ws, size_t ws_size,
                              hipStream_t stream)
{
    const float* fnode  = (const float*)d_in[0];
    const float* fmess  = (const float*)d_in[1];
    const int*   agraph = (const int*)  d_in[2];
    const int*   bgraph = (const int*)  d_in[3];
    const float* mask   = (const float*)d_in[4];
    const float* W_z    = (const float*)d_in[5];
    const float* b_z    = (const float*)d_in[6];
    const float* W_r    = (const float*)d_in[7];
    const float* U_r    = (const float*)d_in[8];
    const float* b_ur   = (const float*)d_in[9];
    const float* W_h    = (const float*)d_in[10];
    const float* b_h    = (const float*)d_in[11];
    const float* W_o    = (const float*)d_in[12];
    const float* b_o    = (const float*)d_in[13];

    const int N = in_sizes[0] / IN_DIM;   // 35000
    const int E = in_sizes[1] / IN_DIM;   // 80000
    const size_t EHu = (size_t)E * H;     // elements per [E,H] plane

    float* out_nodes = (float*)d_out;                    // [N,H] fp32
    float* hA        = (float*)d_out + (size_t)N * H;    // [E,H] fp32 final h
    unsigned short* hb0 = (unsigned short*)hA;           // bf16 ping
    unsigned short* hb1 = hb0 + EHu;                     // bf16 pong (fallback)

    // --- ws layout (ushort units): weight planes | rx zx hx g | smh smg ---
    unsigned short* wb = (unsigned short*)d_ws;
    unsigned short* wzx_hi = wb;                 // Wz[0:128]  [256][128]
    unsigned short* wzx_lo = wb + 32768;
    unsigned short* whx_hi = wb + 65536;         // Wh[0:128]
    unsigned short* whx_lo = wb + 98304;
    unsigned short* wr_hi  = wb + 131072;        // W_r
    unsigned short* wr_lo  = wb + 163840;
    unsigned short* wz2_hi = wb + 196608;        // Wz[128:384] [256][256]
    unsigned short* wz2_lo = wb + 262144;
    unsigned short* wh2_hi = wb + 327680;        // Wh[128:384]
    unsigned short* wh2_lo = wb + 393216;
    unsigned short* ur_hi  = wb + 458752;        // U_r [256][256]
    unsigned short* ur_lo  = wb + 524288;
    unsigned short* wo_hi  = wb + 589824;        // W_o [256][384]
    unsigned short* wo_lo  = wb + 688128;        // ends at 786432
    unsigned short* rxb = wb + 786432;
    unsigned short* zxb = rxb + EHu;
    unsigned short* hxb = zxb + EHu;
    unsigned short* gb  = hxb + EHu;
    unsigned short* smh = gb + EHu;

    const size_t ws_u = ws_size / 2;
    const size_t base_u = 786432 + 4 * EHu;      // planes + rx,zx,hx,g
    const int CH = (base_u + 2 * EHu <= ws_u) ? E : E / 2;   // 40000 fallback
    unsigned short* smg = smh + (size_t)CH * H;

    const dim3 blk(256);
    #define GG(M)  dim3(((M) + 127) / 128, 2)
    #define GU(M)  dim3(((M) + 127) / 128, 4)

    // ---- weight planes ----
    wconv_kernel<<<128, blk, 0, stream>>>(W_z,            wzx_hi, wzx_lo, 128);
    wconv_kernel<<<128, blk, 0, stream>>>(W_h,            whx_hi, whx_lo, 128);
    wconv_kernel<<<128, blk, 0, stream>>>(W_r,            wr_hi,  wr_lo,  128);
    wconv_kernel<<<256, blk, 0, stream>>>(W_z + 128 * H,  wz2_hi, wz2_lo, 256);
    wconv_kernel<<<256, blk, 0, stream>>>(W_h + 128 * H,  wh2_hi, wh2_lo, 256);
    wconv_kernel<<<256, blk, 0, stream>>>(U_r,            ur_hi,  ur_lo,  256);
    wconv_kernel<<<384, blk, 0, stream>>>(W_o,            wo_hi,  wo_lo,  384);

    // ---- loop-invariant precompute: rx+b_ur, zx+b_z, hx+b_h (bf16) ----
    precompute3_kernel<<<GU(E), blk, 0, stream>>>(
        fmess, wr_hi, wr_lo, wzx_hi, wzx_lo, whx_hi, whx_lo,
        b_ur, b_z, b_h, rxb, zxb, hxb, E);

    // ---- step 0: h = sig(zx)*tanh(hx) ----
    step0_kernel<<<(int)((EHu / 4 + 255) / 256), blk, 0, stream>>>(
        zxb, hxb, hb0, (long)(EHu / 4));

    unsigned short* hcur = hb0;
    unsigned short* hnxt = (CH == E) ? hb0 : hb1;   // in-place when unchunked
    for (int t = 1; t < 5; t++) {
        mfma_gemm_kernel<0, true, false, true><<<GG(E), blk, 0, stream>>>(
            hcur, H, nullptr, 0, ur_hi, ur_lo, nullptr, nullptr, gb, E);
        for (int c0 = 0; c0 < E; c0 += CH) {
            const int cc = (E - c0 < CH) ? (E - c0) : CH;
            edge_kernel<<<(cc + 3) / 4, blk, 0, stream>>>(
                hcur, gb, rxb + (size_t)c0 * H, bgraph + (size_t)c0 * NB,
                smh, smg, cc);
            if (t < 4)
                mfma_update2_kernel<false><<<GU(cc), blk, 0, stream>>>(
                    smh, smg, wz2_hi, wz2_lo, wh2_hi, wh2_lo,
                    zxb + (size_t)c0 * H, hxb + (size_t)c0 * H,
                    hnxt + (size_t)c0 * H, cc, c0);
            else
                mfma_update2_kernel<true><<<GU(cc), blk, 0, stream>>>(
                    smh, smg, wz2_hi, wz2_lo, wh2_hi, wh2_lo,
                    zxb + (size_t)c0 * H, hxb + (size_t)c0 * H,
                    hA + (size_t)c0 * H, cc, c0);
        }
        unsigned short* tmp = hcur; hcur = hnxt; hnxt = tmp;
    }

    // ---- readout ----
    node_gather_kernel<<<(N + 3) / 4, blk, 0, stream>>>(hA, agraph, gb, N);
    mfma_gemm_kernel<1, false, true, false><<<GG(N), blk, 0, stream>>>(
        fnode, IN_DIM, gb, H, wo_hi, wo_lo, b_o, mask, out_nodes, N);
    #undef GG
    #undef GU
}